// Round 7
// baseline (243.017 us; speedup 1.0000x reference)
//
#include <hip/hip_runtime.h>
#include <math.h>

#define Bn 8
#define Tn 2048
#define En 1024
#define Hn 128
#define SQRTH 11.313708498984761f

typedef __attribute__((ext_vector_type(8))) short short8;
typedef __attribute__((ext_vector_type(4))) short short4v;
typedef __attribute__((ext_vector_type(4))) float float4v;

#define MFMA16(a, b, c) __builtin_amdgcn_mfma_f32_16x16x32_bf16((a), (b), (c), 0, 0, 0)

static __device__ __forceinline__ unsigned short f2bf(float f) {
    unsigned u = __float_as_uint(f);
    u += 0x7FFFu + ((u >> 16) & 1u);   // RNE
    return (unsigned short)(u >> 16);
}
static __device__ __forceinline__ float bf2f(unsigned short h) {
    return __uint_as_float(((unsigned)h) << 16);
}

// async global->LDS, 16 B per lane. LDS dest is wave-uniform base + lane*16.
static __device__ __forceinline__ void gll16(const unsigned short* g, unsigned short* l) {
    __builtin_amdgcn_global_load_lds(
        (const __attribute__((address_space(1))) unsigned int*)g,
        (__attribute__((address_space(3))) unsigned int*)l, 16, 0, 0);
}

// ---------------------------------------------------------------------------
// SWIZZLES (baked into GLOBAL layouts; all readers adjust):
//  - q/k rows (128 shorts = 16 x 16B blocks): block j of row t at j^(t&15).
//  - vtt rows (32 shorts = 4 blocks): block j of row h at j^((h>>1)&3).
//  - xt/wtt rows (32 shorts = 4 blocks): block j of row r at j^(r&3).
//
// R9: chunked partials+combines. R11: single-buffer staging; 230.7.
// R12: proj swizzle; 218.9. R13: XCD batch affinity grid (B,chunks); 208.7.
// R14: 8-wave blocks REGRESSED (222.3) -> independent 256-thr block streams
// are the latency hider; reverted.
// R15: out_part convoy removal. All staged operands are linear aliases of
// global and L2-resident after R13 affinity (K+V ~1.5 MB/batch vs 4 MB XCD
// L2). Read K/V fragments DIRECTLY from L2 (identical offset math), delete
// staging + both barriers. 4 independent waves/block, LDS 29->5 KB. L2
// amplification ~103 MB/XCD ~ 24 us BW < 42 us of current stall time.
// ---------------------------------------------------------------------------

// ---------------------------------------------------------------------------
// Kernel 0: W (E,H) fp32 -> K-tiled split bf16 wtt[z][ks][128 h][32 k],
// 16B blocks swizzled j^(h&3).
// ---------------------------------------------------------------------------
__global__ __launch_bounds__(256) void wtrans_kernel(
    const float* __restrict__ Wq, const float* __restrict__ Wk, const float* __restrict__ Wv,
    unsigned short* __restrict__ wtt_hi, unsigned short* __restrict__ wtt_lo)
{
    int t = blockIdx.x * 256 + threadIdx.x;   // 0..49151
    int kc8 = t & 3;
    int hh = (t >> 2) & 127;
    int ks = (t >> 9) & 31;
    int z = t >> 14;
    const float* W = (z == 0) ? Wq : ((z == 1) ? Wk : Wv);
    short8 h8, l8;
#pragma unroll
    for (int j = 0; j < 8; j++) {
        int e = ks * 32 + kc8 * 8 + j;
        float v = W[(size_t)e * Hn + hh];
        unsigned short hi = f2bf(v);
        h8[j] = (short)hi;
        l8[j] = (short)f2bf(v - bf2f(hi));
    }
    size_t d = (((size_t)z * 32 + ks) * 4096) + (size_t)hh * 32
             + (size_t)(kc8 ^ (hh & 3)) * 8;            // R12 swizzle
    *(short8*)(wtt_hi + d) = h8;
    *(short8*)(wtt_lo + d) = l8;
}

// ---------------------------------------------------------------------------
// Kernel 0b: x fp32 -> K-tiled split bf16 xt[mt][ks][64 r][32 k],
// 16B blocks swizzled j^(r&3).
// ---------------------------------------------------------------------------
__global__ __launch_bounds__(256) void xconv_kernel(
    const float* __restrict__ x,
    unsigned short* __restrict__ xt_hi, unsigned short* __restrict__ xt_lo)
{
    int g = blockIdx.x * 256 + threadIdx.x;   // 0..2097151
    int kc8 = g & 3;
    int rr = (g >> 2) & 63;
    int ks = (g >> 8) & 31;
    int mt = g >> 13;
    size_t src = ((size_t)mt * 64 + rr) * En + ks * 32 + kc8 * 8;
    float4v f0 = *(const float4v*)(x + src);
    float4v f1 = *(const float4v*)(x + src + 4);
    short8 h, l;
#pragma unroll
    for (int j = 0; j < 4; j++) {
        unsigned short h0 = f2bf(f0[j]);
        h[j] = (short)h0; l[j] = (short)f2bf(f0[j] - bf2f(h0));
        unsigned short h1 = f2bf(f1[j]);
        h[j + 4] = (short)h1; l[j + 4] = (short)f2bf(f1[j] - bf2f(h1));
    }
    size_t d = (size_t)(g >> 2) * 32 + (size_t)(kc8 ^ (rr & 3)) * 8;  // R12
    *(short8*)(xt_hi + d) = h;
    *(short8*)(xt_lo + d) = l;
}

// ---------------------------------------------------------------------------
// Kernel 1: projections, LDS double-buffered GEMM. Swizzle-aware fragment
// reads (kg ^ (c15&3)); staging addresses hoisted into register arrays.
// (Unchanged — harness-verified.)
// ---------------------------------------------------------------------------
__global__ __launch_bounds__(256) void proj_kernel(
    const unsigned short* __restrict__ xt_hi, const unsigned short* __restrict__ xt_lo,
    const unsigned short* __restrict__ wtt_hi, const unsigned short* __restrict__ wtt_lo,
    unsigned short* __restrict__ q_hi, unsigned short* __restrict__ q_lo,
    unsigned short* __restrict__ k_hi, unsigned short* __restrict__ k_lo,
    unsigned short* __restrict__ vtt)
{
    __shared__ __align__(16) unsigned short lds[2][12288];  // 48 KB
    int z = blockIdx.y;
    int mt = blockIdx.x;                       // 0..255
    int tid = threadIdx.x;
    int wave = tid >> 6, lane = tid & 63;
    int c15 = lane & 15, kg = lane >> 4;
    int sb = c15 & 3;                          // read-swizzle selector
    int mrow = wave >> 1, ncol = wave & 1;     // 2x2 wave grid

    const unsigned short* Ah0 = xt_hi + (size_t)mt * 32 * 2048;
    const unsigned short* Al0 = xt_lo + (size_t)mt * 32 * 2048;
    const unsigned short* Bh0 = wtt_hi + (size_t)z * 32 * 4096;
    const unsigned short* Bl0 = wtt_lo + (size_t)z * 32 * 4096;

    float4v acc[2][4];
#pragma unroll
    for (int i = 0; i < 2; i++)
#pragma unroll
        for (int j = 0; j < 4; j++) acc[i][j] = (float4v)0.0f;

    const unsigned short* gcur[6];
    int lbo[6];
    int gstep[6];
    if (z < 2) {
#pragma unroll
        for (int i = 0; i < 6; i++) {
            int ch = wave * 6 + i;
            if (ch < 4)       { gcur[i] = Ah0 + ch * 512;        lbo[i] = ch * 512;               gstep[i] = 2048; }
            else if (ch < 8)  { gcur[i] = Al0 + (ch - 4) * 512;  lbo[i] = 2048 + (ch - 4) * 512;  gstep[i] = 2048; }
            else if (ch < 16) { gcur[i] = Bh0 + (ch - 8) * 512;  lbo[i] = 4096 + (ch - 8) * 512;  gstep[i] = 4096; }
            else              { gcur[i] = Bl0 + (ch - 16) * 512; lbo[i] = 8192 + (ch - 16) * 512; gstep[i] = 4096; }
        }
    } else {
#pragma unroll
        for (int i = 0; i < 3; i++) {
            int ch = wave * 3 + i;   // 0..11
            if (ch < 4) { gcur[i] = Ah0 + ch * 512;       lbo[i] = ch * 512;              gstep[i] = 2048; }
            else        { gcur[i] = Bh0 + (ch - 4) * 512; lbo[i] = 4096 + (ch - 4) * 512; gstep[i] = 4096; }
        }
    }
    int lo8 = lane * 8;

    auto stage = [&](int buf) {
        unsigned short* Lb = lds[0] + buf * 12288;
        if (z < 2) {
#pragma unroll
            for (int i = 0; i < 6; i++) {
                gll16(gcur[i] + lo8, Lb + lbo[i] + lo8);
                gcur[i] += gstep[i];
            }
        } else {
#pragma unroll
            for (int i = 0; i < 3; i++) {
                gll16(gcur[i] + lo8, Lb + lbo[i] + lo8);
                gcur[i] += gstep[i];
            }
        }
    };

    stage(0);

    for (int ks = 0; ks < 32; ks++) {
        __syncthreads();
        if (ks + 1 < 32) stage((ks + 1) & 1);
        const unsigned short* Lb = lds[ks & 1];

        short8 ah[2], al[2], bh[4], bl[4];
#pragma unroll
        for (int mi = 0; mi < 2; mi++) {
            int row = mrow * 32 + mi * 16 + c15;
            ah[mi] = *(const short8*)(Lb + row * 32 + (kg ^ sb) * 8);
        }
#pragma unroll
        for (int ni = 0; ni < 4; ni++) {
            int row = ncol * 64 + ni * 16 + c15;
            bh[ni] = *(const short8*)(Lb + 4096 + row * 32 + (kg ^ sb) * 8);
        }
        if (z < 2) {
#pragma unroll
            for (int mi = 0; mi < 2; mi++) {
                int row = mrow * 32 + mi * 16 + c15;
                al[mi] = *(const short8*)(Lb + 2048 + row * 32 + (kg ^ sb) * 8);
            }
#pragma unroll
            for (int ni = 0; ni < 4; ni++) {
                int row = ncol * 64 + ni * 16 + c15;
                bl[ni] = *(const short8*)(Lb + 8192 + row * 32 + (kg ^ sb) * 8);
            }
#pragma unroll
            for (int mi = 0; mi < 2; mi++)
#pragma unroll
                for (int ni = 0; ni < 4; ni++) {
                    acc[mi][ni] = MFMA16(ah[mi], bh[ni], acc[mi][ni]);
                    acc[mi][ni] = MFMA16(ah[mi], bl[ni], acc[mi][ni]);
                    acc[mi][ni] = MFMA16(al[mi], bh[ni], acc[mi][ni]);
                }
        } else {
#pragma unroll
            for (int mi = 0; mi < 2; mi++)
#pragma unroll
                for (int ni = 0; ni < 4; ni++)
                    acc[mi][ni] = MFMA16(ah[mi], bh[ni], acc[mi][ni]);
        }
    }

    if (z < 2) {
        unsigned short* oh = (z == 0) ? q_hi : k_hi;
        unsigned short* ol = (z == 0) ? q_lo : k_lo;
#pragma unroll
        for (int mi = 0; mi < 2; mi++) {
#pragma unroll
            for (int ni = 0; ni < 4; ni++) {
                int h = ncol * 64 + ni * 16 + c15;
#pragma unroll
                for (int r = 0; r < 4; r++) {
                    int t = mt * 64 + mrow * 32 + mi * 16 + kg * 4 + r;
                    float v = acc[mi][ni][r];
                    unsigned short hh = f2bf(v);
                    unsigned short ll = f2bf(v - bf2f(hh));
                    // swizzled: block (h>>3) of row t -> (h>>3) ^ (t&15)
                    size_t o = (size_t)t * Hn + (((h >> 3) ^ (t & 15)) << 3) + (h & 7);
                    oh[o] = hh;
                    ol[o] = ll;
                }
            }
        }
    } else {
        int b = mt >> 5;
#pragma unroll
        for (int mi = 0; mi < 2; mi++) {
            int t0 = (mt & 31) * 64 + mrow * 32 + mi * 16 + kg * 4;
            int sc = t0 >> 5, so = t0 & 31;
#pragma unroll
            for (int ni = 0; ni < 4; ni++) {
                int h = ncol * 64 + ni * 16 + c15;
                short4v pk;
#pragma unroll
                for (int r = 0; r < 4; r++) pk[r] = (short)f2bf(acc[mi][ni][r]);
                // swizzled: block (so>>3) of row h -> (so>>3) ^ ((h>>1)&3)
                int so2 = ((((so >> 3) ^ ((h >> 1) & 3))) << 3) | (so & 7);
                *(short4v*)(vtt + (((size_t)b * 64 + sc) * 128 + h) * 32 + so2) = pk;
            }
        }
    }
}

// ---------------------------------------------------------------------------
// Kernel 2: column softmax stats PARTIALS. t-loop of column tile sj split
// into nch = ((31-sj)>>2)+1 even chunks (<=8 iters). Single-buffer staging.
// grid (B, 144): batch on x -> XCD affinity; sj ascending = heavy first.
// (Exact R13 form — verified at 208.7.)
// ---------------------------------------------------------------------------
__global__ __launch_bounds__(256) void stats_part_kernel(
    const unsigned short* __restrict__ q_hi, const unsigned short* __restrict__ q_lo,
    const unsigned short* __restrict__ k_hi, const unsigned short* __restrict__ k_lo,
    float* __restrict__ m_part, float* __restrict__ l_part)
{
    __shared__ __align__(16) unsigned short lds[8192];  // 16 KB, single buffer
    int tid = threadIdx.x;
    int wave = tid >> 6, lane = tid & 63;
    int c15 = lane & 15, kg = lane >> 4;
    int b = blockIdx.x;                       // XCD = b

    // map blockIdx.y -> (sj, ci); sj ascending = heavy first
    int rem = (int)blockIdx.y, sj, nch = 1;
    for (sj = 0; sj < 32; sj++) {
        nch = ((31 - sj) >> 2) + 1;
        if (rem < nch) break;
        rem -= nch;
    }
    int ci = rem;
    int c0 = 2 * sj;
    int len = 64 - c0;
    int cbase = len / nch, ext = len % nch;
    int cs = c0 + ci * cbase + (ci < ext ? ci : ext);
    int ce = cs + cbase + (ci < ext ? 1 : 0);

    int s_base = sj * 64 + wave * 16;

    // A fragments: wave's 16 k-rows; s&15 == c15 (s_base is x16-aligned)
    short8 a_h[4], a_l[4];
    {
        int s = s_base + c15;
        const unsigned short* kr = k_hi + ((size_t)(b * Tn + s)) * Hn;
        const unsigned short* krl = k_lo + ((size_t)(b * Tn + s)) * Hn;
#pragma unroll
        for (int st = 0; st < 4; st++) {
            int off = ((st * 4 + kg) ^ c15) * 8;
            a_h[st] = *(const short8*)(kr + off);
            a_l[st] = *(const short8*)(krl + off);
        }
    }
    float m[4], l[4];
#pragma unroll
    for (int r = 0; r < 4; r++) { m[r] = -3.0e38f; l[r] = 0.0f; }

    auto stage = [&](int c) {
        const unsigned short* Qh = q_hi + ((size_t)b * Tn + c * 32) * Hn;
        const unsigned short* Ql = q_lo + ((size_t)b * Tn + c * 32) * Hn;
        int lo8 = lane * 8;
#pragma unroll
        for (int i = 0; i < 4; i++) {
            int ch = wave * 4 + i;   // 0..15
            const unsigned short* g;
            unsigned short* ld;
            if (ch < 8) { g = Qh + ch * 512;       ld = lds + ch * 512; }
            else        { g = Ql + (ch - 8) * 512; ld = lds + 4096 + (ch - 8) * 512; }
            gll16(g + lo8, ld + lo8);
        }
    };

    for (int c = cs; c < ce; c++) {
        stage(c);
        __syncthreads();   // stage complete
#pragma unroll
        for (int half = 0; half < 2; half++) {
            int t16 = c * 32 + half * 16;
            int tl = half * 16 + c15;
            float4v a1 = (float4v)0.0f, a2 = (float4v)0.0f, a3 = (float4v)0.0f;
#pragma unroll
            for (int st = 0; st < 4; st++) {
                // swizzled block ((st*4+kg) ^ (t&15)); t&15 == c15
                int off = tl * 128 + ((st * 4 + kg) ^ c15) * 8;
                short8 bh = *(const short8*)(lds + off);
                short8 bl = *(const short8*)(lds + 4096 + off);
                a1 = MFMA16(a_h[st], bh, a1);
                a2 = MFMA16(a_h[st], bl, a2);
                a3 = MFMA16(a_l[st], bh, a3);
            }
            int t = t16 + c15;
#pragma unroll
            for (int r = 0; r < 4; r++) {
                float attv = (a1[r] + a2[r] + a3[r]) * SQRTH;
                int s_row = s_base + kg * 4 + r;
                bool valid = (t >= s_row);
                float cand = valid ? attv : -3.0e38f;
                float mn = fmaxf(m[r], cand);
                l[r] = l[r] * __expf(m[r] - mn) + (valid ? __expf(attv - mn) : 0.0f);
                m[r] = mn;
            }
        }
        __syncthreads();   // all reads done before next stage overwrites
    }
    // merge t-subsets across the 16 lanes sharing kg
#pragma unroll
    for (int mask = 1; mask < 16; mask <<= 1) {
#pragma unroll
        for (int r = 0; r < 4; r++) {
            float mo = __shfl_xor(m[r], mask);
            float lo2 = __shfl_xor(l[r], mask);
            float mn = fmaxf(m[r], mo);
            l[r] = l[r] * __expf(m[r] - mn) + lo2 * __expf(mo - mn);
            m[r] = mn;
        }
    }
    if (c15 == 0) {
#pragma unroll
        for (int r = 0; r < 4; r++) {
            int sl = wave * 16 + kg * 4 + r;           // 0..63 within tile
            size_t d = ((((size_t)b * 32 + sj) * 8 + ci) * 64) + sl;
            m_part[d] = m[r];
            l_part[d] = l[r];
        }
    }
}

// ---------------------------------------------------------------------------
// Kernel 2b: merge stats partials -> (m_st, il_st). 16384 columns.
// ---------------------------------------------------------------------------
__global__ __launch_bounds__(256) void stats_combine_kernel(
    const float* __restrict__ m_part, const float* __restrict__ l_part,
    float* __restrict__ m_st, float* __restrict__ il_st)
{
    int g = blockIdx.x * 256 + threadIdx.x;   // 0..16383
    int s = g & 2047, b = g >> 11;
    int sj = s >> 6, sl = s & 63;
    int nch = ((31 - sj) >> 2) + 1;
    size_t base = (((size_t)b * 32 + sj) * 8) * 64 + sl;
    float M = m_part[base];
    float L = l_part[base];
    for (int ci = 1; ci < nch; ci++) {
        float mi = m_part[base + (size_t)ci * 64];
        float li = l_part[base + (size_t)ci * 64];
        float mn = fmaxf(M, mi);
        L = L * __expf(M - mn) + li * __expf(mi - mn);
        M = mn;
    }
    m_st[(size_t)b * Tn + s] = M;
    il_st[(size_t)b * Tn + s] = 1.0f / L;
}

// ---------------------------------------------------------------------------
// Kernel 3: output PARTIALS. R15: barrier-free streaming. K/V fragments
// read DIRECTLY from global (L2-resident after R13 XCD affinity; offsets
// identical to the former staged-LDS layout since gll16 copied linearly).
// No staging, no __syncthreads; pbuf transpose is wave-internal (DS
// in-order). s-loop of row tile tj split into nch = (tj>>2)+1 chunks
// (<=8 iters). grid (B, 144): XCD affinity; tj descending = heavy first.
// ---------------------------------------------------------------------------
__global__ __launch_bounds__(256) void out_part_kernel(
    const unsigned short* __restrict__ q_hi, const unsigned short* __restrict__ q_lo,
    const unsigned short* __restrict__ k_hi, const unsigned short* __restrict__ k_lo,
    const unsigned short* __restrict__ vtt,
    const float* __restrict__ m_st, const float* __restrict__ il_st,
    float* __restrict__ part_out)
{
    __shared__ __align__(16) unsigned short pbuf[4][16][40]; // 5 KB only
    int tid = threadIdx.x;
    int wave = tid >> 6, lane = tid & 63;
    int c15 = lane & 15, kg = lane >> 4;
    int b = blockIdx.x;                       // XCD = b

    // map blockIdx.y -> (tj, ci); tj descending = heavy first
    int rem = (int)blockIdx.y, tj, nch = 1;
    for (tj = 31; tj >= 0; tj--) {
        nch = (tj >> 2) + 1;
        if (rem < nch) break;
        rem -= nch;
    }
    int ci = rem;
    int len = 2 * tj + 2;
    int cbase = len / nch, ext = len % nch;
    int cs = ci * cbase + (ci < ext ? ci : ext);
    int ce = cs + cbase + (ci < ext ? 1 : 0);

    int t_base = tj * 64 + wave * 16;

    // A fragments: wave's 16 q-rows; t&15 == c15
    short8 qa_h[4], qa_l[4];
    {
        int t = t_base + c15;
        const unsigned short* qr = q_hi + ((size_t)(b * Tn + t)) * Hn;
        const unsigned short* qrl = q_lo + ((size_t)(b * Tn + t)) * Hn;
#pragma unroll
        for (int st = 0; st < 4; st++) {
            int off = ((st * 4 + kg) ^ c15) * 8;
            qa_h[st] = *(const short8*)(qr + off);
            qa_l[st] = *(const short8*)(qrl + off);
        }
    }
    float4v oacc[8];
#pragma unroll
    for (int i = 0; i < 8; i++) oacc[i] = (float4v)0.0f;

    for (int c = cs; c < ce; c++) {
        const unsigned short* Kh = k_hi + ((size_t)b * Tn + c * 32) * Hn;
        const unsigned short* Kl = k_lo + ((size_t)b * Tn + c * 32) * Hn;
        const unsigned short* Vv = vtt + ((size_t)b * 64 + c) * (128 * 32);
#pragma unroll
        for (int half = 0; half < 2; half++) {
            int s16 = c * 32 + half * 16;
            int sl = half * 16 + c15;
            float4v a1 = (float4v)0.0f, a2 = (float4v)0.0f, a3 = (float4v)0.0f;
#pragma unroll
            for (int st = 0; st < 4; st++) {
                // swizzled block ((st*4+kg) ^ (s&15)); s&15 == c15
                int off = sl * 128 + ((st * 4 + kg) ^ c15) * 8;
                short8 bh = *(const short8*)(Kh + off);     // direct L2
                short8 bl = *(const short8*)(Kl + off);     // direct L2
                a1 = MFMA16(qa_h[st], bh, a1);
                a2 = MFMA16(qa_h[st], bl, a2);
                a3 = MFMA16(qa_l[st], bh, a3);
            }
            float msv = m_st[b * Tn + s16 + c15];
            float ilv = il_st[b * Tn + s16 + c15];
#pragma unroll
            for (int r = 0; r < 4; r++) {
                int t = t_base + kg * 4 + r;
                float attv = (a1[r] + a2[r] + a3[r]) * SQRTH;
                // clamp: att <= column max for true data (ULP-exact safety)
                float earg = fminf(attv - msv, 0.0f);
                float p = (t >= s16 + c15) ? __expf(earg) * ilv : 0.0f;
                pbuf[wave][kg * 4 + r][c15 + half * 16] = f2bf(p);
            }
        }
        // C-layout -> A-layout via LDS (wave-internal, DS pipe in-order)
        short8 pa = *(const short8*)&pbuf[wave][c15][kg * 8];
#pragma unroll
        for (int nt = 0; nt < 8; nt++) {
            // vtt row h = nt*16+c15; swizzled block kg ^ ((h>>1)&3),
            // (h>>1)&3 == (c15>>1)&3 since nt*16 is a multiple of 8 in h>>1
            int voff = (nt * 16 + c15) * 32 + ((kg ^ ((c15 >> 1) & 3)) * 8);
            short8 vb = *(const short8*)(Vv + voff);        // direct L2
            oacc[nt] = MFMA16(pa, vb, oacc[nt]);
        }
    }
    // partial tile store: part[b][tj][ci][t_local 64][h 128]
    float* po = part_out + ((((size_t)b * 32 + tj) * 8 + ci) * 64) * 128;
#pragma unroll
    for (int nt = 0; nt < 8; nt++) {
        int h = nt * 16 + c15;
#pragma unroll
        for (int r = 0; r < 4; r++) {
            int tl = wave * 16 + kg * 4 + r;
            po[(size_t)tl * 128 + h] = oacc[nt][r];
        }
    }
}

// ---------------------------------------------------------------------------
// Kernel 3b: sum output partials -> out. 2M floats, float4 loads/stores.
// ---------------------------------------------------------------------------
__global__ __launch_bounds__(256) void out_combine_kernel(
    const float* __restrict__ part_out, float* __restrict__ out)
{
    int g = blockIdx.x * 256 + threadIdx.x;   // 0..524287 (float4 units)
    int h4 = g & 31;
    int t = (g >> 5) & 2047;
    int b = g >> 16;
    int tj = t >> 6, tl = t & 63;
    int nch = (tj >> 2) + 1;
    const float4v* p = (const float4v*)(part_out
        + ((((size_t)b * 32 + tj) * 8) * 64 + tl) * 128) + h4;
    float4v acc = p[0];
    for (int ci = 1; ci < nch; ci++) acc += p[(size_t)ci * 2048];  // slot = 8192 floats
    *((float4v*)(out + ((size_t)b * Tn + t) * Hn) + h4) = acc;
}

// ---------------------------------------------------------------------------
extern "C" void kernel_launch(void* const* d_in, const int* in_sizes, int n_in,
                              void* d_out, int out_size, void* d_ws, size_t ws_size,
                              hipStream_t stream)
{
    (void)in_sizes; (void)n_in; (void)out_size; (void)ws_size;
    const float* x  = (const float*)d_in[0];
    const float* Wk = (const float*)d_in[1];
    const float* Wq = (const float*)d_in[2];
    const float* Wv = (const float*)d_in[3];
    float* out = (float*)d_out;

    const size_t NQ = (size_t)Bn * Tn * Hn;        // 2,097,152
    const size_t NX = (size_t)Bn * Tn * En;        // 16,777,216
    unsigned short* q_hi = (unsigned short*)d_ws;
    unsigned short* q_lo = q_hi + NQ;
    unsigned short* k_hi = q_lo + NQ;
    unsigned short* k_lo = k_hi + NQ;
    unsigned short* vtt  = k_lo + NQ;
    unsigned short* xt_hi = vtt + NQ;
    unsigned short* xt_lo = xt_hi + NX;
    unsigned short* wtt_hi = xt_lo + NX;
    unsigned short* wtt_lo = wtt_hi + (size_t)3 * Hn * En;
    float* m_st  = (float*)(wtt_lo + (size_t)3 * Hn * En);
    float* il_st = m_st + (size_t)Bn * Tn;
    // total ws use: ~89.4 MB — identical extent to the validated R7 layout

    // Dead-after-proj aliases:
    //  part_out = xt region: 8*32*8*64*128 fp32 = 67.1 MB == sizeof(xt_hi+xt_lo)
    //  m_part/l_part = wtt region: 8*32*8*64 fp32 = 512 KB each (<= 768 KB)
    float* part_out = (float*)xt_hi;
    float* m_part   = (float*)wtt_hi;
    float* l_part   = (float*)wtt_lo;

    wtrans_kernel<<<dim3(192), 256, 0, stream>>>(Wq, Wk, Wv, wtt_hi, wtt_lo);
    xconv_kernel<<<dim3(8192), 256, 0, stream>>>(x, xt_hi, xt_lo);
    proj_kernel<<<dim3(256, 3), 256, 0, stream>>>(xt_hi, xt_lo, wtt_hi, wtt_lo,
                                                  q_hi, q_lo, k_hi, k_lo, vtt);
    stats_part_kernel<<<dim3(Bn, 144), 256, 0, stream>>>(q_hi, q_lo, k_hi, k_lo,
                                                         m_part, l_part);
    stats_combine_kernel<<<dim3(64), 256, 0, stream>>>(m_part, l_part, m_st, il_st);
    out_part_kernel<<<dim3(Bn, 144), 256, 0, stream>>>(q_hi, q_lo, k_hi, k_lo, vtt,
                                                       m_st, il_st, part_out);
    out_combine_kernel<<<dim3(2048), 256, 0, stream>>>(part_out, out);
}

// Round 8
// 223.004 us; speedup vs baseline: 1.0897x; 1.0897x over previous
//
#include <hip/hip_runtime.h>
#include <math.h>

#define Bn 8
#define Tn 2048
#define En 1024
#define Hn 128
#define SQRTH 11.313708498984761f

typedef __attribute__((ext_vector_type(8))) short short8;
typedef __attribute__((ext_vector_type(4))) short short4v;
typedef __attribute__((ext_vector_type(4))) float float4v;

#define MFMA16(a, b, c) __builtin_amdgcn_mfma_f32_16x16x32_bf16((a), (b), (c), 0, 0, 0)

static __device__ __forceinline__ unsigned short f2bf(float f) {
    unsigned u = __float_as_uint(f);
    u += 0x7FFFu + ((u >> 16) & 1u);   // RNE
    return (unsigned short)(u >> 16);
}
static __device__ __forceinline__ float bf2f(unsigned short h) {
    return __uint_as_float(((unsigned)h) << 16);
}

// async global->LDS, 16 B per lane. LDS dest is wave-uniform base + lane*16.
static __device__ __forceinline__ void gll16(const unsigned short* g, unsigned short* l) {
    __builtin_amdgcn_global_load_lds(
        (const __attribute__((address_space(1))) unsigned int*)g,
        (__attribute__((address_space(3))) unsigned int*)l, 16, 0, 0);
}

// ---------------------------------------------------------------------------
// SWIZZLES (baked into GLOBAL layouts; all readers adjust):
//  - q/k rows (128 shorts = 16 x 16B blocks): block j of row t at j^(t&15).
//  - vtt rows (32 shorts = 4 blocks): block j of row h at j^((h>>1)&3).
//  - xt/wtt rows (32 shorts = 4 blocks): block j of row r at j^(r&3).
//
// R9: chunked partials+combines. R11: single-buffer staging; 230.7.
// R12: proj swizzle; 218.9. R13: XCD batch affinity grid (B,chunks); 208.7.
// R14: 8-wave blocks REGRESSED (222.3): independent 256-thr block streams
// are the latency hider. R15: direct-L2 reads REGRESSED (243; FETCH 60->11
// MB but dur up): scattered per-lane global loads serialize at ~200cy —
// staging's bulk DMA is the right form; its cost is the 2-barrier convoy.
// R16: port proj_kernel's HARNESS-VERIFIED double-buffer loop (prologue
// stage(0); per-iter barrier -> stage(next) -> compute(cur); hoisted
// monotonic cursors, uniform +4096 stride) into stats_part and out_part.
// One barrier/iter, loads in flight under compute. Geometry = exact R13.
// ---------------------------------------------------------------------------

// ---------------------------------------------------------------------------
// Kernel 0: W (E,H) fp32 -> K-tiled split bf16 wtt[z][ks][128 h][32 k],
// 16B blocks swizzled j^(h&3).
// ---------------------------------------------------------------------------
__global__ __launch_bounds__(256) void wtrans_kernel(
    const float* __restrict__ Wq, const float* __restrict__ Wk, const float* __restrict__ Wv,
    unsigned short* __restrict__ wtt_hi, unsigned short* __restrict__ wtt_lo)
{
    int t = blockIdx.x * 256 + threadIdx.x;   // 0..49151
    int kc8 = t & 3;
    int hh = (t >> 2) & 127;
    int ks = (t >> 9) & 31;
    int z = t >> 14;
    const float* W = (z == 0) ? Wq : ((z == 1) ? Wk : Wv);
    short8 h8, l8;
#pragma unroll
    for (int j = 0; j < 8; j++) {
        int e = ks * 32 + kc8 * 8 + j;
        float v = W[(size_t)e * Hn + hh];
        unsigned short hi = f2bf(v);
        h8[j] = (short)hi;
        l8[j] = (short)f2bf(v - bf2f(hi));
    }
    size_t d = (((size_t)z * 32 + ks) * 4096) + (size_t)hh * 32
             + (size_t)(kc8 ^ (hh & 3)) * 8;            // R12 swizzle
    *(short8*)(wtt_hi + d) = h8;
    *(short8*)(wtt_lo + d) = l8;
}

// ---------------------------------------------------------------------------
// Kernel 0b: x fp32 -> K-tiled split bf16 xt[mt][ks][64 r][32 k],
// 16B blocks swizzled j^(r&3).
// ---------------------------------------------------------------------------
__global__ __launch_bounds__(256) void xconv_kernel(
    const float* __restrict__ x,
    unsigned short* __restrict__ xt_hi, unsigned short* __restrict__ xt_lo)
{
    int g = blockIdx.x * 256 + threadIdx.x;   // 0..2097151
    int kc8 = g & 3;
    int rr = (g >> 2) & 63;
    int ks = (g >> 8) & 31;
    int mt = g >> 13;
    size_t src = ((size_t)mt * 64 + rr) * En + ks * 32 + kc8 * 8;
    float4v f0 = *(const float4v*)(x + src);
    float4v f1 = *(const float4v*)(x + src + 4);
    short8 h, l;
#pragma unroll
    for (int j = 0; j < 4; j++) {
        unsigned short h0 = f2bf(f0[j]);
        h[j] = (short)h0; l[j] = (short)f2bf(f0[j] - bf2f(h0));
        unsigned short h1 = f2bf(f1[j]);
        h[j + 4] = (short)h1; l[j + 4] = (short)f2bf(f1[j] - bf2f(h1));
    }
    size_t d = (size_t)(g >> 2) * 32 + (size_t)(kc8 ^ (rr & 3)) * 8;  // R12
    *(short8*)(xt_hi + d) = h;
    *(short8*)(xt_lo + d) = l;
}

// ---------------------------------------------------------------------------
// Kernel 1: projections, LDS double-buffered GEMM. Swizzle-aware fragment
// reads (kg ^ (c15&3)); staging addresses hoisted into register arrays.
// (Unchanged — harness-verified.)
// ---------------------------------------------------------------------------
__global__ __launch_bounds__(256) void proj_kernel(
    const unsigned short* __restrict__ xt_hi, const unsigned short* __restrict__ xt_lo,
    const unsigned short* __restrict__ wtt_hi, const unsigned short* __restrict__ wtt_lo,
    unsigned short* __restrict__ q_hi, unsigned short* __restrict__ q_lo,
    unsigned short* __restrict__ k_hi, unsigned short* __restrict__ k_lo,
    unsigned short* __restrict__ vtt)
{
    __shared__ __align__(16) unsigned short lds[2][12288];  // 48 KB
    int z = blockIdx.y;
    int mt = blockIdx.x;                       // 0..255
    int tid = threadIdx.x;
    int wave = tid >> 6, lane = tid & 63;
    int c15 = lane & 15, kg = lane >> 4;
    int sb = c15 & 3;                          // read-swizzle selector
    int mrow = wave >> 1, ncol = wave & 1;     // 2x2 wave grid

    const unsigned short* Ah0 = xt_hi + (size_t)mt * 32 * 2048;
    const unsigned short* Al0 = xt_lo + (size_t)mt * 32 * 2048;
    const unsigned short* Bh0 = wtt_hi + (size_t)z * 32 * 4096;
    const unsigned short* Bl0 = wtt_lo + (size_t)z * 32 * 4096;

    float4v acc[2][4];
#pragma unroll
    for (int i = 0; i < 2; i++)
#pragma unroll
        for (int j = 0; j < 4; j++) acc[i][j] = (float4v)0.0f;

    const unsigned short* gcur[6];
    int lbo[6];
    int gstep[6];
    if (z < 2) {
#pragma unroll
        for (int i = 0; i < 6; i++) {
            int ch = wave * 6 + i;
            if (ch < 4)       { gcur[i] = Ah0 + ch * 512;        lbo[i] = ch * 512;               gstep[i] = 2048; }
            else if (ch < 8)  { gcur[i] = Al0 + (ch - 4) * 512;  lbo[i] = 2048 + (ch - 4) * 512;  gstep[i] = 2048; }
            else if (ch < 16) { gcur[i] = Bh0 + (ch - 8) * 512;  lbo[i] = 4096 + (ch - 8) * 512;  gstep[i] = 4096; }
            else              { gcur[i] = Bl0 + (ch - 16) * 512; lbo[i] = 8192 + (ch - 16) * 512; gstep[i] = 4096; }
        }
    } else {
#pragma unroll
        for (int i = 0; i < 3; i++) {
            int ch = wave * 3 + i;   // 0..11
            if (ch < 4) { gcur[i] = Ah0 + ch * 512;       lbo[i] = ch * 512;              gstep[i] = 2048; }
            else        { gcur[i] = Bh0 + (ch - 4) * 512; lbo[i] = 4096 + (ch - 4) * 512; gstep[i] = 4096; }
        }
    }
    int lo8 = lane * 8;

    auto stage = [&](int buf) {
        unsigned short* Lb = lds[0] + buf * 12288;
        if (z < 2) {
#pragma unroll
            for (int i = 0; i < 6; i++) {
                gll16(gcur[i] + lo8, Lb + lbo[i] + lo8);
                gcur[i] += gstep[i];
            }
        } else {
#pragma unroll
            for (int i = 0; i < 3; i++) {
                gll16(gcur[i] + lo8, Lb + lbo[i] + lo8);
                gcur[i] += gstep[i];
            }
        }
    };

    stage(0);

    for (int ks = 0; ks < 32; ks++) {
        __syncthreads();
        if (ks + 1 < 32) stage((ks + 1) & 1);
        const unsigned short* Lb = lds[ks & 1];

        short8 ah[2], al[2], bh[4], bl[4];
#pragma unroll
        for (int mi = 0; mi < 2; mi++) {
            int row = mrow * 32 + mi * 16 + c15;
            ah[mi] = *(const short8*)(Lb + row * 32 + (kg ^ sb) * 8);
        }
#pragma unroll
        for (int ni = 0; ni < 4; ni++) {
            int row = ncol * 64 + ni * 16 + c15;
            bh[ni] = *(const short8*)(Lb + 4096 + row * 32 + (kg ^ sb) * 8);
        }
        if (z < 2) {
#pragma unroll
            for (int mi = 0; mi < 2; mi++) {
                int row = mrow * 32 + mi * 16 + c15;
                al[mi] = *(const short8*)(Lb + 2048 + row * 32 + (kg ^ sb) * 8);
            }
#pragma unroll
            for (int ni = 0; ni < 4; ni++) {
                int row = ncol * 64 + ni * 16 + c15;
                bl[ni] = *(const short8*)(Lb + 8192 + row * 32 + (kg ^ sb) * 8);
            }
#pragma unroll
            for (int mi = 0; mi < 2; mi++)
#pragma unroll
                for (int ni = 0; ni < 4; ni++) {
                    acc[mi][ni] = MFMA16(ah[mi], bh[ni], acc[mi][ni]);
                    acc[mi][ni] = MFMA16(ah[mi], bl[ni], acc[mi][ni]);
                    acc[mi][ni] = MFMA16(al[mi], bh[ni], acc[mi][ni]);
                }
        } else {
#pragma unroll
            for (int mi = 0; mi < 2; mi++)
#pragma unroll
                for (int ni = 0; ni < 4; ni++)
                    acc[mi][ni] = MFMA16(ah[mi], bh[ni], acc[mi][ni]);
        }
    }

    if (z < 2) {
        unsigned short* oh = (z == 0) ? q_hi : k_hi;
        unsigned short* ol = (z == 0) ? q_lo : k_lo;
#pragma unroll
        for (int mi = 0; mi < 2; mi++) {
#pragma unroll
            for (int ni = 0; ni < 4; ni++) {
                int h = ncol * 64 + ni * 16 + c15;
#pragma unroll
                for (int r = 0; r < 4; r++) {
                    int t = mt * 64 + mrow * 32 + mi * 16 + kg * 4 + r;
                    float v = acc[mi][ni][r];
                    unsigned short hh = f2bf(v);
                    unsigned short ll = f2bf(v - bf2f(hh));
                    // swizzled: block (h>>3) of row t -> (h>>3) ^ (t&15)
                    size_t o = (size_t)t * Hn + (((h >> 3) ^ (t & 15)) << 3) + (h & 7);
                    oh[o] = hh;
                    ol[o] = ll;
                }
            }
        }
    } else {
        int b = mt >> 5;
#pragma unroll
        for (int mi = 0; mi < 2; mi++) {
            int t0 = (mt & 31) * 64 + mrow * 32 + mi * 16 + kg * 4;
            int sc = t0 >> 5, so = t0 & 31;
#pragma unroll
            for (int ni = 0; ni < 4; ni++) {
                int h = ncol * 64 + ni * 16 + c15;
                short4v pk;
#pragma unroll
                for (int r = 0; r < 4; r++) pk[r] = (short)f2bf(acc[mi][ni][r]);
                // swizzled: block (so>>3) of row h -> (so>>3) ^ ((h>>1)&3)
                int so2 = ((((so >> 3) ^ ((h >> 1) & 3))) << 3) | (so & 7);
                *(short4v*)(vtt + (((size_t)b * 64 + sc) * 128 + h) * 32 + so2) = pk;
            }
        }
    }
}

// ---------------------------------------------------------------------------
// Kernel 2: column softmax stats PARTIALS. t-loop of column tile sj split
// into nch = ((31-sj)>>2)+1 even chunks (<=8 iters). R16: proj-pattern
// double-buffer (hoisted cursors, one barrier/iter). grid (B, 144).
// ---------------------------------------------------------------------------
__global__ __launch_bounds__(256) void stats_part_kernel(
    const unsigned short* __restrict__ q_hi, const unsigned short* __restrict__ q_lo,
    const unsigned short* __restrict__ k_hi, const unsigned short* __restrict__ k_lo,
    float* __restrict__ m_part, float* __restrict__ l_part)
{
    __shared__ __align__(16) unsigned short lds[2][8192];  // 32 KB
    int tid = threadIdx.x;
    int wave = tid >> 6, lane = tid & 63;
    int c15 = lane & 15, kg = lane >> 4;
    int b = blockIdx.x;                       // XCD = b

    // map blockIdx.y -> (sj, ci); sj ascending = heavy first
    int rem = (int)blockIdx.y, sj, nch = 1;
    for (sj = 0; sj < 32; sj++) {
        nch = ((31 - sj) >> 2) + 1;
        if (rem < nch) break;
        rem -= nch;
    }
    int ci = rem;
    int c0 = 2 * sj;
    int len = 64 - c0;
    int cbase = len / nch, ext = len % nch;
    int cs = c0 + ci * cbase + (ci < ext ? ci : ext);
    int ce = cs + cbase + (ci < ext ? 1 : 0);

    int s_base = sj * 64 + wave * 16;

    // A fragments: wave's 16 k-rows; s&15 == c15 (s_base is x16-aligned)
    short8 a_h[4], a_l[4];
    {
        int s = s_base + c15;
        const unsigned short* kr = k_hi + ((size_t)(b * Tn + s)) * Hn;
        const unsigned short* krl = k_lo + ((size_t)(b * Tn + s)) * Hn;
#pragma unroll
        for (int st = 0; st < 4; st++) {
            int off = ((st * 4 + kg) ^ c15) * 8;
            a_h[st] = *(const short8*)(kr + off);
            a_l[st] = *(const short8*)(krl + off);
        }
    }
    float m[4], l[4];
#pragma unroll
    for (int r = 0; r < 4; r++) { m[r] = -3.0e38f; l[r] = 0.0f; }

    // hoisted staging cursors (proj pattern): 4 chunks/wave, stride 4096/c
    const unsigned short* gcur[4];
    int lbo[4];
    {
        const unsigned short* Qh = q_hi + ((size_t)b * Tn + cs * 32) * Hn;
        const unsigned short* Ql = q_lo + ((size_t)b * Tn + cs * 32) * Hn;
#pragma unroll
        for (int i = 0; i < 4; i++) {
            int ch = wave * 4 + i;   // 0..15
            if (ch < 8) { gcur[i] = Qh + ch * 512;       lbo[i] = ch * 512; }
            else        { gcur[i] = Ql + (ch - 8) * 512; lbo[i] = 4096 + (ch - 8) * 512; }
        }
    }
    int lo8 = lane * 8;

    auto stage = [&](int buf) {
        unsigned short* Lb = lds[0] + buf * 8192;
#pragma unroll
        for (int i = 0; i < 4; i++) {
            gll16(gcur[i] + lo8, Lb + lbo[i] + lo8);
            gcur[i] += 4096;
        }
    };

    stage(0);
    for (int c = cs; c < ce; c++) {
        __syncthreads();                       // buf[(c-cs)&1] ready; prev reads done
        if (c + 1 < ce) stage((c - cs + 1) & 1);
        const unsigned short* Lb = lds[0] + ((c - cs) & 1) * 8192;
#pragma unroll
        for (int half = 0; half < 2; half++) {
            int t16 = c * 32 + half * 16;
            int tl = half * 16 + c15;
            float4v a1 = (float4v)0.0f, a2 = (float4v)0.0f, a3 = (float4v)0.0f;
#pragma unroll
            for (int st = 0; st < 4; st++) {
                // swizzled block ((st*4+kg) ^ (t&15)); t&15 == c15
                int off = tl * 128 + ((st * 4 + kg) ^ c15) * 8;
                short8 bh = *(const short8*)(Lb + off);
                short8 bl = *(const short8*)(Lb + 4096 + off);
                a1 = MFMA16(a_h[st], bh, a1);
                a2 = MFMA16(a_h[st], bl, a2);
                a3 = MFMA16(a_l[st], bh, a3);
            }
            int t = t16 + c15;
#pragma unroll
            for (int r = 0; r < 4; r++) {
                float attv = (a1[r] + a2[r] + a3[r]) * SQRTH;
                int s_row = s_base + kg * 4 + r;
                bool valid = (t >= s_row);
                float cand = valid ? attv : -3.0e38f;
                float mn = fmaxf(m[r], cand);
                l[r] = l[r] * __expf(m[r] - mn) + (valid ? __expf(attv - mn) : 0.0f);
                m[r] = mn;
            }
        }
    }
    // merge t-subsets across the 16 lanes sharing kg
#pragma unroll
    for (int mask = 1; mask < 16; mask <<= 1) {
#pragma unroll
        for (int r = 0; r < 4; r++) {
            float mo = __shfl_xor(m[r], mask);
            float lo2 = __shfl_xor(l[r], mask);
            float mn = fmaxf(m[r], mo);
            l[r] = l[r] * __expf(m[r] - mn) + lo2 * __expf(mo - mn);
            m[r] = mn;
        }
    }
    if (c15 == 0) {
#pragma unroll
        for (int r = 0; r < 4; r++) {
            int sl = wave * 16 + kg * 4 + r;           // 0..63 within tile
            size_t d = ((((size_t)b * 32 + sj) * 8 + ci) * 64) + sl;
            m_part[d] = m[r];
            l_part[d] = l[r];
        }
    }
}

// ---------------------------------------------------------------------------
// Kernel 2b: merge stats partials -> (m_st, il_st). 16384 columns.
// ---------------------------------------------------------------------------
__global__ __launch_bounds__(256) void stats_combine_kernel(
    const float* __restrict__ m_part, const float* __restrict__ l_part,
    float* __restrict__ m_st, float* __restrict__ il_st)
{
    int g = blockIdx.x * 256 + threadIdx.x;   // 0..16383
    int s = g & 2047, b = g >> 11;
    int sj = s >> 6, sl = s & 63;
    int nch = ((31 - sj) >> 2) + 1;
    size_t base = (((size_t)b * 32 + sj) * 8) * 64 + sl;
    float M = m_part[base];
    float L = l_part[base];
    for (int ci = 1; ci < nch; ci++) {
        float mi = m_part[base + (size_t)ci * 64];
        float li = l_part[base + (size_t)ci * 64];
        float mn = fmaxf(M, mi);
        L = L * __expf(M - mn) + li * __expf(mi - mn);
        M = mn;
    }
    m_st[(size_t)b * Tn + s] = M;
    il_st[(size_t)b * Tn + s] = 1.0f / L;
}

// ---------------------------------------------------------------------------
// Kernel 3: output PARTIALS. s-loop of row tile tj split into nch =
// (tj>>2)+1 even chunks (<=8 iters). R16: staged-LDS reads (R13 form)
// with proj-pattern double-buffer (one barrier/iter). grid (B, 144).
// ---------------------------------------------------------------------------
__global__ __launch_bounds__(256) void out_part_kernel(
    const unsigned short* __restrict__ q_hi, const unsigned short* __restrict__ q_lo,
    const unsigned short* __restrict__ k_hi, const unsigned short* __restrict__ k_lo,
    const unsigned short* __restrict__ vtt,
    const float* __restrict__ m_st, const float* __restrict__ il_st,
    float* __restrict__ part_out)
{
    __shared__ __align__(16) unsigned short lds[2][12288];   // 48 KB
    __shared__ __align__(16) unsigned short pbuf[4][16][40]; // 5 KB
    int tid = threadIdx.x;
    int wave = tid >> 6, lane = tid & 63;
    int c15 = lane & 15, kg = lane >> 4;
    int b = blockIdx.x;                       // XCD = b

    // map blockIdx.y -> (tj, ci); tj descending = heavy first
    int rem = (int)blockIdx.y, tj, nch = 1;
    for (tj = 31; tj >= 0; tj--) {
        nch = (tj >> 2) + 1;
        if (rem < nch) break;
        rem -= nch;
    }
    int ci = rem;
    int len = 2 * tj + 2;
    int cbase = len / nch, ext = len % nch;
    int cs = ci * cbase + (ci < ext ? ci : ext);
    int ce = cs + cbase + (ci < ext ? 1 : 0);

    int t_base = tj * 64 + wave * 16;

    // A fragments: wave's 16 q-rows; t&15 == c15
    short8 qa_h[4], qa_l[4];
    {
        int t = t_base + c15;
        const unsigned short* qr = q_hi + ((size_t)(b * Tn + t)) * Hn;
        const unsigned short* qrl = q_lo + ((size_t)(b * Tn + t)) * Hn;
#pragma unroll
        for (int st = 0; st < 4; st++) {
            int off = ((st * 4 + kg) ^ c15) * 8;
            qa_h[st] = *(const short8*)(qr + off);
            qa_l[st] = *(const short8*)(qrl + off);
        }
    }
    float4v oacc[8];
#pragma unroll
    for (int i = 0; i < 8; i++) oacc[i] = (float4v)0.0f;

    // hoisted staging cursors (proj pattern): 6 chunks/wave, stride 4096/c
    const unsigned short* gcur[6];
    int lbo[6];
    {
        const unsigned short* Kh = k_hi + ((size_t)b * Tn + cs * 32) * Hn;
        const unsigned short* Kl = k_lo + ((size_t)b * Tn + cs * 32) * Hn;
        const unsigned short* Vv = vtt + ((size_t)b * 64 + cs) * (128 * 32);
#pragma unroll
        for (int i = 0; i < 6; i++) {
            int ch = wave * 6 + i;   // 0..23
            if (ch < 8)       { gcur[i] = Kh + ch * 512;        lbo[i] = ch * 512; }
            else if (ch < 16) { gcur[i] = Kl + (ch - 8) * 512;  lbo[i] = 4096 + (ch - 8) * 512; }
            else              { gcur[i] = Vv + (ch - 16) * 512; lbo[i] = 8192 + (ch - 16) * 512; }
        }
    }
    int lo8 = lane * 8;

    auto stage = [&](int buf) {
        unsigned short* Lb = lds[0] + buf * 12288;
#pragma unroll
        for (int i = 0; i < 6; i++) {
            gll16(gcur[i] + lo8, Lb + lbo[i] + lo8);
            gcur[i] += 4096;
        }
    };

    stage(0);
    for (int c = cs; c < ce; c++) {
        __syncthreads();                       // buf[(c-cs)&1] ready; prev reads done
        if (c + 1 < ce) stage((c - cs + 1) & 1);
        const unsigned short* Lb = lds[0] + ((c - cs) & 1) * 12288;
#pragma unroll
        for (int half = 0; half < 2; half++) {
            int s16 = c * 32 + half * 16;
            int sl = half * 16 + c15;
            float4v a1 = (float4v)0.0f, a2 = (float4v)0.0f, a3 = (float4v)0.0f;
#pragma unroll
            for (int st = 0; st < 4; st++) {
                // swizzled block ((st*4+kg) ^ (s&15)); s&15 == c15
                int off = sl * 128 + ((st * 4 + kg) ^ c15) * 8;
                short8 bh = *(const short8*)(Lb + off);
                short8 bl = *(const short8*)(Lb + 4096 + off);
                a1 = MFMA16(qa_h[st], bh, a1);
                a2 = MFMA16(qa_h[st], bl, a2);
                a3 = MFMA16(qa_l[st], bh, a3);
            }
            float msv = m_st[b * Tn + s16 + c15];
            float ilv = il_st[b * Tn + s16 + c15];
#pragma unroll
            for (int r = 0; r < 4; r++) {
                int t = t_base + kg * 4 + r;
                float attv = (a1[r] + a2[r] + a3[r]) * SQRTH;
                // clamp: att <= column max for true data (ULP-exact safety)
                float earg = fminf(attv - msv, 0.0f);
                float p = (t >= s16 + c15) ? __expf(earg) * ilv : 0.0f;
                pbuf[wave][kg * 4 + r][c15 + half * 16] = f2bf(p);
            }
        }
        // C-layout -> A-layout via LDS (wave-internal, DS pipe in-order)
        short8 pa = *(const short8*)&pbuf[wave][c15][kg * 8];
#pragma unroll
        for (int nt = 0; nt < 8; nt++) {
            // vtt row h = nt*16+c15; swizzled block kg ^ ((h>>1)&3),
            // (h>>1)&3 == (c15>>1)&3 since nt*16 is a multiple of 8 in h>>1
            int voff = (nt * 16 + c15) * 32 + ((kg ^ ((c15 >> 1) & 3)) * 8);
            short8 vb = *(const short8*)(Lb + 8192 + voff);
            oacc[nt] = MFMA16(pa, vb, oacc[nt]);
        }
    }
    // partial tile store: part[b][tj][ci][t_local 64][h 128]
    float* po = part_out + ((((size_t)b * 32 + tj) * 8 + ci) * 64) * 128;
#pragma unroll
    for (int nt = 0; nt < 8; nt++) {
        int h = nt * 16 + c15;
#pragma unroll
        for (int r = 0; r < 4; r++) {
            int tl = wave * 16 + kg * 4 + r;
            po[(size_t)tl * 128 + h] = oacc[nt][r];
        }
    }
}

// ---------------------------------------------------------------------------
// Kernel 3b: sum output partials -> out. 2M floats, float4 loads/stores.
// ---------------------------------------------------------------------------
__global__ __launch_bounds__(256) void out_combine_kernel(
    const float* __restrict__ part_out, float* __restrict__ out)
{
    int g = blockIdx.x * 256 + threadIdx.x;   // 0..524287 (float4 units)
    int h4 = g & 31;
    int t = (g >> 5) & 2047;
    int b = g >> 16;
    int tj = t >> 6, tl = t & 63;
    int nch = (tj >> 2) + 1;
    const float4v* p = (const float4v*)(part_out
        + ((((size_t)b * 32 + tj) * 8) * 64 + tl) * 128) + h4;
    float4v acc = p[0];
    for (int ci = 1; ci < nch; ci++) acc += p[(size_t)ci * 2048];  // slot = 8192 floats
    *((float4v*)(out + ((size_t)b * Tn + t) * Hn) + h4) = acc;
}

// ---------------------------------------------------------------------------
extern "C" void kernel_launch(void* const* d_in, const int* in_sizes, int n_in,
                              void* d_out, int out_size, void* d_ws, size_t ws_size,
                              hipStream_t stream)
{
    (void)in_sizes; (void)n_in; (void)out_size; (void)ws_size;
    const float* x  = (const float*)d_in[0];
    const float* Wk = (const float*)d_in[1];
    const float* Wq = (const float*)d_in[2];
    const float* Wv = (const float*)d_in[3];
    float* out = (float*)d_out;

    const size_t NQ = (size_t)Bn * Tn * Hn;        // 2,097,152
    const size_t NX = (size_t)Bn * Tn * En;        // 16,777,216
    unsigned short* q_hi = (unsigned short*)d_ws;
    unsigned short* q_lo = q_hi + NQ;
    unsigned short* k_hi = q_lo + NQ;
    unsigned short* k_lo = k_hi + NQ;
    unsigned short* vtt  = k_lo + NQ;
    unsigned short* xt_hi = vtt + NQ;
    unsigned short* xt_lo = xt_hi + NX;
    unsigned short* wtt_hi = xt_lo + NX;
    unsigned short* wtt_lo = wtt_hi + (size_t)3 * Hn * En;
    float* m_st  = (float*)(wtt_lo + (size_t)3 * Hn * En);
    float* il_st = m_st + (size_t)Bn * Tn;
    // total ws use: ~89.4 MB — identical extent to the validated R7 layout

    // Dead-after-proj aliases:
    //  part_out = xt region: 8*32*8*64*128 fp32 = 67.1 MB == sizeof(xt_hi+xt_lo)
    //  m_part/l_part = wtt region: 8*32*8*64 fp32 = 512 KB each (<= 768 KB)
    float* part_out = (float*)xt_hi;
    float* m_part   = (float*)wtt_hi;
    float* l_part   = (float*)wtt_lo;

    wtrans_kernel<<<dim3(192), 256, 0, stream>>>(Wq, Wk, Wv, wtt_hi, wtt_lo);
    xconv_kernel<<<dim3(8192), 256, 0, stream>>>(x, xt_hi, xt_lo);
    proj_kernel<<<dim3(256, 3), 256, 0, stream>>>(xt_hi, xt_lo, wtt_hi, wtt_lo,
                                                  q_hi, q_lo, k_hi, k_lo, vtt);
    stats_part_kernel<<<dim3(Bn, 144), 256, 0, stream>>>(q_hi, q_lo, k_hi, k_lo,
                                                         m_part, l_part);
    stats_combine_kernel<<<dim3(64), 256, 0, stream>>>(m_part, l_part, m_st, il_st);
    out_part_kernel<<<dim3(Bn, 144), 256, 0, stream>>>(q_hi, q_lo, k_hi, k_lo, vtt,
                                                       m_st, il_st, part_out);
    out_combine_kernel<<<dim3(2048), 256, 0, stream>>>(part_out, out);
}

// Round 9
// 197.913 us; speedup vs baseline: 1.2279x; 1.1268x over previous
//
#include <hip/hip_runtime.h>
#include <math.h>

#define Bn 8
#define Tn 2048
#define En 1024
#define Hn 128
#define SQRTH 11.313708498984761f

typedef __attribute__((ext_vector_type(8))) short short8;
typedef __attribute__((ext_vector_type(8))) _Float16 half8;
typedef __attribute__((ext_vector_type(4))) short short4v;
typedef __attribute__((ext_vector_type(4))) float float4v;

#define MFMA16(a, b, c)  __builtin_amdgcn_mfma_f32_16x16x32_bf16((a), (b), (c), 0, 0, 0)
#define MFMA16F(a, b, c) __builtin_amdgcn_mfma_f32_16x16x32_f16((a), (b), (c), 0, 0, 0)

static __device__ __forceinline__ unsigned short f2bf(float f) {
    unsigned u = __float_as_uint(f);
    u += 0x7FFFu + ((u >> 16) & 1u);   // RNE
    return (unsigned short)(u >> 16);
}
static __device__ __forceinline__ float bf2f(unsigned short h) {
    return __uint_as_float(((unsigned)h) << 16);
}
static __device__ __forceinline__ unsigned short f2h(float f) {
    _Float16 h = (_Float16)f;          // RNE
    union { _Float16 v; unsigned short u; } c; c.v = h; return c.u;
}

// async global->LDS, 16 B per lane. LDS dest is wave-uniform base + lane*16.
static __device__ __forceinline__ void gll16(const unsigned short* g, unsigned short* l) {
    __builtin_amdgcn_global_load_lds(
        (const __attribute__((address_space(1))) unsigned int*)g,
        (__attribute__((address_space(3))) unsigned int*)l, 16, 0, 0);
}

// ---------------------------------------------------------------------------
// SWIZZLES (baked into GLOBAL layouts; all readers adjust):
//  - q/k rows (128 shorts = 16 x 16B blocks): block j of row t at j^(t&15).
//  - vtt rows (32 shorts = 4 blocks): block j of row h at j^((h>>1)&3).
//  - xt/wtt rows (32 shorts = 4 blocks): block j of row r at j^(r&3).
//
// R9 chunked partials; R11 single-buffer staging (230.7); R12 proj swizzle
// (218.9); R13 XCD batch affinity (208.7 = best); R14 8-wave REGRESSED
// (TLP is the latency hider); R15 direct-L2 REGRESSED (scattered loads
// serialize; bulk-DMA staging is right); R16 dbuf REGRESSED (LDS x2 ->
// occupancy /2).
// R17: attack the WORK, not the schedule. Q/K stored as fp16 (2^-11 rel
// precision; att err ~0.04 of scale-52 att values, common-mode cancels in
// softmax) -> QK^T is ONE fp16 MFMA pass instead of 3 split-bf16 passes in
// BOTH stats and out; staged bytes drop (stats 16->8 KB/iter, out 24->16);
// out LDS 29.7->21 KB (7 blocks/CU). proj GEMM keeps split-bf16 inputs
// (q/k accuracy), epilogue stores fp16 single-buffer. Geometry = exact R13.
// ---------------------------------------------------------------------------

// ---------------------------------------------------------------------------
// Kernel 0: W (E,H) fp32 -> K-tiled split bf16 wtt[z][ks][128 h][32 k],
// 16B blocks swizzled j^(h&3).
// ---------------------------------------------------------------------------
__global__ __launch_bounds__(256) void wtrans_kernel(
    const float* __restrict__ Wq, const float* __restrict__ Wk, const float* __restrict__ Wv,
    unsigned short* __restrict__ wtt_hi, unsigned short* __restrict__ wtt_lo)
{
    int t = blockIdx.x * 256 + threadIdx.x;   // 0..49151
    int kc8 = t & 3;
    int hh = (t >> 2) & 127;
    int ks = (t >> 9) & 31;
    int z = t >> 14;
    const float* W = (z == 0) ? Wq : ((z == 1) ? Wk : Wv);
    short8 h8, l8;
#pragma unroll
    for (int j = 0; j < 8; j++) {
        int e = ks * 32 + kc8 * 8 + j;
        float v = W[(size_t)e * Hn + hh];
        unsigned short hi = f2bf(v);
        h8[j] = (short)hi;
        l8[j] = (short)f2bf(v - bf2f(hi));
    }
    size_t d = (((size_t)z * 32 + ks) * 4096) + (size_t)hh * 32
             + (size_t)(kc8 ^ (hh & 3)) * 8;            // R12 swizzle
    *(short8*)(wtt_hi + d) = h8;
    *(short8*)(wtt_lo + d) = l8;
}

// ---------------------------------------------------------------------------
// Kernel 0b: x fp32 -> K-tiled split bf16 xt[mt][ks][64 r][32 k],
// 16B blocks swizzled j^(r&3).
// ---------------------------------------------------------------------------
__global__ __launch_bounds__(256) void xconv_kernel(
    const float* __restrict__ x,
    unsigned short* __restrict__ xt_hi, unsigned short* __restrict__ xt_lo)
{
    int g = blockIdx.x * 256 + threadIdx.x;   // 0..2097151
    int kc8 = g & 3;
    int rr = (g >> 2) & 63;
    int ks = (g >> 8) & 31;
    int mt = g >> 13;
    size_t src = ((size_t)mt * 64 + rr) * En + ks * 32 + kc8 * 8;
    float4v f0 = *(const float4v*)(x + src);
    float4v f1 = *(const float4v*)(x + src + 4);
    short8 h, l;
#pragma unroll
    for (int j = 0; j < 4; j++) {
        unsigned short h0 = f2bf(f0[j]);
        h[j] = (short)h0; l[j] = (short)f2bf(f0[j] - bf2f(h0));
        unsigned short h1 = f2bf(f1[j]);
        h[j + 4] = (short)h1; l[j + 4] = (short)f2bf(f1[j] - bf2f(h1));
    }
    size_t d = (size_t)(g >> 2) * 32 + (size_t)(kc8 ^ (rr & 3)) * 8;  // R12
    *(short8*)(xt_hi + d) = h;
    *(short8*)(xt_lo + d) = l;
}

// ---------------------------------------------------------------------------
// Kernel 1: projections, LDS double-buffered GEMM (verified structure).
// R17: q/k epilogue stores fp16 single-buffer (same swizzle).
// ---------------------------------------------------------------------------
__global__ __launch_bounds__(256) void proj_kernel(
    const unsigned short* __restrict__ xt_hi, const unsigned short* __restrict__ xt_lo,
    const unsigned short* __restrict__ wtt_hi, const unsigned short* __restrict__ wtt_lo,
    unsigned short* __restrict__ qf, unsigned short* __restrict__ kf,
    unsigned short* __restrict__ vtt)
{
    __shared__ __align__(16) unsigned short lds[2][12288];  // 48 KB
    int z = blockIdx.y;
    int mt = blockIdx.x;                       // 0..255
    int tid = threadIdx.x;
    int wave = tid >> 6, lane = tid & 63;
    int c15 = lane & 15, kg = lane >> 4;
    int sb = c15 & 3;                          // read-swizzle selector
    int mrow = wave >> 1, ncol = wave & 1;     // 2x2 wave grid

    const unsigned short* Ah0 = xt_hi + (size_t)mt * 32 * 2048;
    const unsigned short* Al0 = xt_lo + (size_t)mt * 32 * 2048;
    const unsigned short* Bh0 = wtt_hi + (size_t)z * 32 * 4096;
    const unsigned short* Bl0 = wtt_lo + (size_t)z * 32 * 4096;

    float4v acc[2][4];
#pragma unroll
    for (int i = 0; i < 2; i++)
#pragma unroll
        for (int j = 0; j < 4; j++) acc[i][j] = (float4v)0.0f;

    const unsigned short* gcur[6];
    int lbo[6];
    int gstep[6];
    if (z < 2) {
#pragma unroll
        for (int i = 0; i < 6; i++) {
            int ch = wave * 6 + i;
            if (ch < 4)       { gcur[i] = Ah0 + ch * 512;        lbo[i] = ch * 512;               gstep[i] = 2048; }
            else if (ch < 8)  { gcur[i] = Al0 + (ch - 4) * 512;  lbo[i] = 2048 + (ch - 4) * 512;  gstep[i] = 2048; }
            else if (ch < 16) { gcur[i] = Bh0 + (ch - 8) * 512;  lbo[i] = 4096 + (ch - 8) * 512;  gstep[i] = 4096; }
            else              { gcur[i] = Bl0 + (ch - 16) * 512; lbo[i] = 8192 + (ch - 16) * 512; gstep[i] = 4096; }
        }
    } else {
#pragma unroll
        for (int i = 0; i < 3; i++) {
            int ch = wave * 3 + i;   // 0..11
            if (ch < 4) { gcur[i] = Ah0 + ch * 512;       lbo[i] = ch * 512;              gstep[i] = 2048; }
            else        { gcur[i] = Bh0 + (ch - 4) * 512; lbo[i] = 4096 + (ch - 4) * 512; gstep[i] = 4096; }
        }
    }
    int lo8 = lane * 8;

    auto stage = [&](int buf) {
        unsigned short* Lb = lds[0] + buf * 12288;
        if (z < 2) {
#pragma unroll
            for (int i = 0; i < 6; i++) {
                gll16(gcur[i] + lo8, Lb + lbo[i] + lo8);
                gcur[i] += gstep[i];
            }
        } else {
#pragma unroll
            for (int i = 0; i < 3; i++) {
                gll16(gcur[i] + lo8, Lb + lbo[i] + lo8);
                gcur[i] += gstep[i];
            }
        }
    };

    stage(0);

    for (int ks = 0; ks < 32; ks++) {
        __syncthreads();
        if (ks + 1 < 32) stage((ks + 1) & 1);
        const unsigned short* Lb = lds[ks & 1];

        short8 ah[2], al[2], bh[4], bl[4];
#pragma unroll
        for (int mi = 0; mi < 2; mi++) {
            int row = mrow * 32 + mi * 16 + c15;
            ah[mi] = *(const short8*)(Lb + row * 32 + (kg ^ sb) * 8);
        }
#pragma unroll
        for (int ni = 0; ni < 4; ni++) {
            int row = ncol * 64 + ni * 16 + c15;
            bh[ni] = *(const short8*)(Lb + 4096 + row * 32 + (kg ^ sb) * 8);
        }
        if (z < 2) {
#pragma unroll
            for (int mi = 0; mi < 2; mi++) {
                int row = mrow * 32 + mi * 16 + c15;
                al[mi] = *(const short8*)(Lb + 2048 + row * 32 + (kg ^ sb) * 8);
            }
#pragma unroll
            for (int ni = 0; ni < 4; ni++) {
                int row = ncol * 64 + ni * 16 + c15;
                bl[ni] = *(const short8*)(Lb + 8192 + row * 32 + (kg ^ sb) * 8);
            }
#pragma unroll
            for (int mi = 0; mi < 2; mi++)
#pragma unroll
                for (int ni = 0; ni < 4; ni++) {
                    acc[mi][ni] = MFMA16(ah[mi], bh[ni], acc[mi][ni]);
                    acc[mi][ni] = MFMA16(ah[mi], bl[ni], acc[mi][ni]);
                    acc[mi][ni] = MFMA16(al[mi], bh[ni], acc[mi][ni]);
                }
        } else {
#pragma unroll
            for (int mi = 0; mi < 2; mi++)
#pragma unroll
                for (int ni = 0; ni < 4; ni++)
                    acc[mi][ni] = MFMA16(ah[mi], bh[ni], acc[mi][ni]);
        }
    }

    if (z < 2) {
        unsigned short* oh = (z == 0) ? qf : kf;
#pragma unroll
        for (int mi = 0; mi < 2; mi++) {
#pragma unroll
            for (int ni = 0; ni < 4; ni++) {
                int h = ncol * 64 + ni * 16 + c15;
#pragma unroll
                for (int r = 0; r < 4; r++) {
                    int t = mt * 64 + mrow * 32 + mi * 16 + kg * 4 + r;
                    // swizzled: block (h>>3) of row t -> (h>>3) ^ (t&15)
                    size_t o = (size_t)t * Hn + (((h >> 3) ^ (t & 15)) << 3) + (h & 7);
                    oh[o] = f2h(acc[mi][ni][r]);        // R17: fp16 single
                }
            }
        }
    } else {
        int b = mt >> 5;
#pragma unroll
        for (int mi = 0; mi < 2; mi++) {
            int t0 = (mt & 31) * 64 + mrow * 32 + mi * 16 + kg * 4;
            int sc = t0 >> 5, so = t0 & 31;
#pragma unroll
            for (int ni = 0; ni < 4; ni++) {
                int h = ncol * 64 + ni * 16 + c15;
                short4v pk;
#pragma unroll
                for (int r = 0; r < 4; r++) pk[r] = (short)f2bf(acc[mi][ni][r]);
                // swizzled: block (so>>3) of row h -> (so>>3) ^ ((h>>1)&3)
                int so2 = ((((so >> 3) ^ ((h >> 1) & 3))) << 3) | (so & 7);
                *(short4v*)(vtt + (((size_t)b * 64 + sc) * 128 + h) * 32 + so2) = pk;
            }
        }
    }
}

// ---------------------------------------------------------------------------
// Kernel 2: column softmax stats PARTIALS. t-loop of column tile sj split
// into nch = ((31-sj)>>2)+1 even chunks (<=8 iters). Single-buffer staging
// (R13 form), fp16 single-pass QK (R17). grid (B, 144): XCD affinity.
// ---------------------------------------------------------------------------
__global__ __launch_bounds__(256) void stats_part_kernel(
    const unsigned short* __restrict__ qf, const unsigned short* __restrict__ kf,
    float* __restrict__ m_part, float* __restrict__ l_part)
{
    __shared__ __align__(16) unsigned short lds[4096];  // 8 KB, single buffer
    int tid = threadIdx.x;
    int wave = tid >> 6, lane = tid & 63;
    int c15 = lane & 15, kg = lane >> 4;
    int b = blockIdx.x;                       // XCD = b

    // map blockIdx.y -> (sj, ci); sj ascending = heavy first
    int rem = (int)blockIdx.y, sj, nch = 1;
    for (sj = 0; sj < 32; sj++) {
        nch = ((31 - sj) >> 2) + 1;
        if (rem < nch) break;
        rem -= nch;
    }
    int ci = rem;
    int c0 = 2 * sj;
    int len = 64 - c0;
    int cbase = len / nch, ext = len % nch;
    int cs = c0 + ci * cbase + (ci < ext ? ci : ext);
    int ce = cs + cbase + (ci < ext ? 1 : 0);

    int s_base = sj * 64 + wave * 16;

    // A fragments: wave's 16 k-rows (fp16); s&15 == c15
    half8 a[4];
    {
        int s = s_base + c15;
        const unsigned short* kr = kf + ((size_t)(b * Tn + s)) * Hn;
#pragma unroll
        for (int st = 0; st < 4; st++) {
            int off = ((st * 4 + kg) ^ c15) * 8;
            a[st] = *(const half8*)(kr + off);
        }
    }
    float m[4], l[4];
#pragma unroll
    for (int r = 0; r < 4; r++) { m[r] = -3.0e38f; l[r] = 0.0f; }

    auto stage = [&](int c) {
        const unsigned short* Qf = qf + ((size_t)b * Tn + c * 32) * Hn;
        int lo8 = lane * 8;
#pragma unroll
        for (int i = 0; i < 2; i++) {
            int ch = wave * 2 + i;   // 0..7
            gll16(Qf + ch * 512 + lo8, lds + ch * 512 + lo8);
        }
    };

    for (int c = cs; c < ce; c++) {
        stage(c);
        __syncthreads();   // stage complete
#pragma unroll
        for (int half = 0; half < 2; half++) {
            int t16 = c * 32 + half * 16;
            int tl = half * 16 + c15;
            float4v a1 = (float4v)0.0f;
#pragma unroll
            for (int st = 0; st < 4; st++) {
                // swizzled block ((st*4+kg) ^ (t&15)); t&15 == c15
                int off = tl * 128 + ((st * 4 + kg) ^ c15) * 8;
                half8 bh = *(const half8*)(lds + off);
                a1 = MFMA16F(a[st], bh, a1);
            }
            int t = t16 + c15;
#pragma unroll
            for (int r = 0; r < 4; r++) {
                float attv = a1[r] * SQRTH;
                int s_row = s_base + kg * 4 + r;
                bool valid = (t >= s_row);
                float cand = valid ? attv : -3.0e38f;
                float mn = fmaxf(m[r], cand);
                l[r] = l[r] * __expf(m[r] - mn) + (valid ? __expf(attv - mn) : 0.0f);
                m[r] = mn;
            }
        }
        __syncthreads();   // all reads done before next stage overwrites
    }
    // merge t-subsets across the 16 lanes sharing kg
#pragma unroll
    for (int mask = 1; mask < 16; mask <<= 1) {
#pragma unroll
        for (int r = 0; r < 4; r++) {
            float mo = __shfl_xor(m[r], mask);
            float lo2 = __shfl_xor(l[r], mask);
            float mn = fmaxf(m[r], mo);
            l[r] = l[r] * __expf(m[r] - mn) + lo2 * __expf(mo - mn);
            m[r] = mn;
        }
    }
    if (c15 == 0) {
#pragma unroll
        for (int r = 0; r < 4; r++) {
            int sl = wave * 16 + kg * 4 + r;           // 0..63 within tile
            size_t d = ((((size_t)b * 32 + sj) * 8 + ci) * 64) + sl;
            m_part[d] = m[r];
            l_part[d] = l[r];
        }
    }
}

// ---------------------------------------------------------------------------
// Kernel 2b: merge stats partials -> (m_st, il_st). 16384 columns.
// ---------------------------------------------------------------------------
__global__ __launch_bounds__(256) void stats_combine_kernel(
    const float* __restrict__ m_part, const float* __restrict__ l_part,
    float* __restrict__ m_st, float* __restrict__ il_st)
{
    int g = blockIdx.x * 256 + threadIdx.x;   // 0..16383
    int s = g & 2047, b = g >> 11;
    int sj = s >> 6, sl = s & 63;
    int nch = ((31 - sj) >> 2) + 1;
    size_t base = (((size_t)b * 32 + sj) * 8) * 64 + sl;
    float M = m_part[base];
    float L = l_part[base];
    for (int ci = 1; ci < nch; ci++) {
        float mi = m_part[base + (size_t)ci * 64];
        float li = l_part[base + (size_t)ci * 64];
        float mn = fmaxf(M, mi);
        L = L * __expf(M - mn) + li * __expf(mi - mn);
        M = mn;
    }
    m_st[(size_t)b * Tn + s] = M;
    il_st[(size_t)b * Tn + s] = 1.0f / L;
}

// ---------------------------------------------------------------------------
// Kernel 3: output PARTIALS. s-loop of row tile tj split into nch =
// (tj>>2)+1 even chunks (<=8 iters). Single-buffer staging (R13 form),
// fp16 single-pass QK + bf16 PV (R17). grid (B, 144): XCD affinity.
// ---------------------------------------------------------------------------
__global__ __launch_bounds__(256) void out_part_kernel(
    const unsigned short* __restrict__ qf, const unsigned short* __restrict__ kf,
    const unsigned short* __restrict__ vtt,
    const float* __restrict__ m_st, const float* __restrict__ il_st,
    float* __restrict__ part_out)
{
    __shared__ __align__(16) unsigned short lds[8192];       // 16 KB, single
    __shared__ __align__(16) unsigned short pbuf[4][16][40]; // 5 KB
    int tid = threadIdx.x;
    int wave = tid >> 6, lane = tid & 63;
    int c15 = lane & 15, kg = lane >> 4;
    int b = blockIdx.x;                       // XCD = b

    // map blockIdx.y -> (tj, ci); tj descending = heavy first
    int rem = (int)blockIdx.y, tj, nch = 1;
    for (tj = 31; tj >= 0; tj--) {
        nch = (tj >> 2) + 1;
        if (rem < nch) break;
        rem -= nch;
    }
    int ci = rem;
    int len = 2 * tj + 2;
    int cbase = len / nch, ext = len % nch;
    int cs = ci * cbase + (ci < ext ? ci : ext);
    int ce = cs + cbase + (ci < ext ? 1 : 0);

    int t_base = tj * 64 + wave * 16;

    // A fragments: wave's 16 q-rows (fp16); t&15 == c15
    half8 qa[4];
    {
        int t = t_base + c15;
        const unsigned short* qr = qf + ((size_t)(b * Tn + t)) * Hn;
#pragma unroll
        for (int st = 0; st < 4; st++) {
            int off = ((st * 4 + kg) ^ c15) * 8;
            qa[st] = *(const half8*)(qr + off);
        }
    }
    float4v oacc[8];
#pragma unroll
    for (int i = 0; i < 8; i++) oacc[i] = (float4v)0.0f;

    auto stage = [&](int c) {
        const unsigned short* Kf = kf + ((size_t)b * Tn + c * 32) * Hn;
        const unsigned short* Vv = vtt + ((size_t)b * 64 + c) * (128 * 32);
        int lo8 = lane * 8;
#pragma unroll
        for (int i = 0; i < 4; i++) {
            int ch = wave * 4 + i;   // 0..15
            const unsigned short* g;
            unsigned short* ld;
            if (ch < 8) { g = Kf + ch * 512;       ld = lds + ch * 512; }
            else        { g = Vv + (ch - 8) * 512; ld = lds + 4096 + (ch - 8) * 512; }
            gll16(g + lo8, ld + lo8);
        }
    };

    for (int c = cs; c < ce; c++) {
        stage(c);
        __syncthreads();   // stage complete
#pragma unroll
        for (int half = 0; half < 2; half++) {
            int s16 = c * 32 + half * 16;
            int sl = half * 16 + c15;
            float4v a1 = (float4v)0.0f;
#pragma unroll
            for (int st = 0; st < 4; st++) {
                // swizzled block ((st*4+kg) ^ (s&15)); s&15 == c15
                int off = sl * 128 + ((st * 4 + kg) ^ c15) * 8;
                half8 bh = *(const half8*)(lds + off);
                a1 = MFMA16F(qa[st], bh, a1);
            }
            float msv = m_st[b * Tn + s16 + c15];
            float ilv = il_st[b * Tn + s16 + c15];
#pragma unroll
            for (int r = 0; r < 4; r++) {
                int t = t_base + kg * 4 + r;
                float attv = a1[r] * SQRTH;
                // clamp: att <= column max for true data (ULP-exact safety)
                float earg = fminf(attv - msv, 0.0f);
                float p = (t >= s16 + c15) ? __expf(earg) * ilv : 0.0f;
                pbuf[wave][kg * 4 + r][c15 + half * 16] = f2bf(p);
            }
        }
        // C-layout -> A-layout via LDS (wave-internal, DS pipe in-order)
        short8 pa = *(const short8*)&pbuf[wave][c15][kg * 8];
#pragma unroll
        for (int nt = 0; nt < 8; nt++) {
            // vtt row h = nt*16+c15; swizzled block kg ^ ((h>>1)&3),
            // (h>>1)&3 == (c15>>1)&3 since nt*16 is a multiple of 8 in h>>1
            int voff = (nt * 16 + c15) * 32 + ((kg ^ ((c15 >> 1) & 3)) * 8);
            short8 vb = *(const short8*)(lds + 4096 + voff);
            oacc[nt] = MFMA16(pa, vb, oacc[nt]);
        }
        __syncthreads();   // all reads done before next stage overwrites
    }
    // partial tile store: part[b][tj][ci][t_local 64][h 128]
    float* po = part_out + ((((size_t)b * 32 + tj) * 8 + ci) * 64) * 128;
#pragma unroll
    for (int nt = 0; nt < 8; nt++) {
        int h = nt * 16 + c15;
#pragma unroll
        for (int r = 0; r < 4; r++) {
            int tl = wave * 16 + kg * 4 + r;
            po[(size_t)tl * 128 + h] = oacc[nt][r];
        }
    }
}

// ---------------------------------------------------------------------------
// Kernel 3b: sum output partials -> out. 2M floats, float4 loads/stores.
// ---------------------------------------------------------------------------
__global__ __launch_bounds__(256) void out_combine_kernel(
    const float* __restrict__ part_out, float* __restrict__ out)
{
    int g = blockIdx.x * 256 + threadIdx.x;   // 0..524287 (float4 units)
    int h4 = g & 31;
    int t = (g >> 5) & 2047;
    int b = g >> 16;
    int tj = t >> 6, tl = t & 63;
    int nch = (tj >> 2) + 1;
    const float4v* p = (const float4v*)(part_out
        + ((((size_t)b * 32 + tj) * 8) * 64 + tl) * 128) + h4;
    float4v acc = p[0];
    for (int ci = 1; ci < nch; ci++) acc += p[(size_t)ci * 2048];  // slot = 8192 floats
    *((float4v*)(out + ((size_t)b * Tn + t) * Hn) + h4) = acc;
}

// ---------------------------------------------------------------------------
extern "C" void kernel_launch(void* const* d_in, const int* in_sizes, int n_in,
                              void* d_out, int out_size, void* d_ws, size_t ws_size,
                              hipStream_t stream)
{
    (void)in_sizes; (void)n_in; (void)out_size; (void)ws_size;
    const float* x  = (const float*)d_in[0];
    const float* Wk = (const float*)d_in[1];
    const float* Wq = (const float*)d_in[2];
    const float* Wv = (const float*)d_in[3];
    float* out = (float*)d_out;

    const size_t NQ = (size_t)Bn * Tn * Hn;        // 2,097,152
    const size_t NX = (size_t)Bn * Tn * En;        // 16,777,216
    unsigned short* qf  = (unsigned short*)d_ws;   // fp16 q (R17)
    unsigned short* qlo = qf + NQ;                 // unused (kept layout)
    unsigned short* kf  = qlo + NQ;                // fp16 k (R17)
    unsigned short* klo = kf + NQ;                 // unused (kept layout)
    unsigned short* vtt  = klo + NQ;
    unsigned short* xt_hi = vtt + NQ;
    unsigned short* xt_lo = xt_hi + NX;
    unsigned short* wtt_hi = xt_lo + NX;
    unsigned short* wtt_lo = wtt_hi + (size_t)3 * Hn * En;
    float* m_st  = (float*)(wtt_lo + (size_t)3 * Hn * En);
    float* il_st = m_st + (size_t)Bn * Tn;
    // total ws use: ~89.4 MB — identical extent to the validated R7 layout

    // Dead-after-proj aliases:
    //  part_out = xt region: 8*32*8*64*128 fp32 = 67.1 MB == sizeof(xt_hi+xt_lo)
    //  m_part/l_part = wtt region: 8*32*8*64 fp32 = 512 KB each (<= 768 KB)
    float* part_out = (float*)xt_hi;
    float* m_part   = (float*)wtt_hi;
    float* l_part   = (float*)wtt_lo;

    wtrans_kernel<<<dim3(192), 256, 0, stream>>>(Wq, Wk, Wv, wtt_hi, wtt_lo);
    xconv_kernel<<<dim3(8192), 256, 0, stream>>>(x, xt_hi, xt_lo);
    proj_kernel<<<dim3(256, 3), 256, 0, stream>>>(xt_hi, xt_lo, wtt_hi, wtt_lo,
                                                  qf, kf, vtt);
    stats_part_kernel<<<dim3(Bn, 144), 256, 0, stream>>>(qf, kf, m_part, l_part);
    stats_combine_kernel<<<dim3(64), 256, 0, stream>>>(m_part, l_part, m_st, il_st);
    out_part_kernel<<<dim3(Bn, 144), 256, 0, stream>>>(qf, kf, vtt,
                                                       m_st, il_st, part_out);
    out_combine_kernel<<<dim3(2048), 256, 0, stream>>>(part_out, out);
}

// Round 10
// 177.800 us; speedup vs baseline: 1.3668x; 1.1131x over previous
//
#include <hip/hip_runtime.h>
#include <math.h>

#define Bn 8
#define Tn 2048
#define En 1024
#define Hn 128
#define SQRTH 11.313708498984761f

typedef __attribute__((ext_vector_type(8))) short short8;
typedef __attribute__((ext_vector_type(8))) _Float16 half8;
typedef __attribute__((ext_vector_type(4))) short short4v;
typedef __attribute__((ext_vector_type(4))) float float4v;

#define MFMA16(a, b, c)  __builtin_amdgcn_mfma_f32_16x16x32_bf16((a), (b), (c), 0, 0, 0)
#define MFMA16F(a, b, c) __builtin_amdgcn_mfma_f32_16x16x32_f16((a), (b), (c), 0, 0, 0)

static __device__ __forceinline__ unsigned short f2bf(float f) {
    unsigned u = __float_as_uint(f);
    u += 0x7FFFu + ((u >> 16) & 1u);   // RNE
    return (unsigned short)(u >> 16);
}
static __device__ __forceinline__ unsigned short f2h(float f) {
    _Float16 h = (_Float16)f;          // RNE
    union { _Float16 v; unsigned short u; } c; c.v = h; return c.u;
}

// async global->LDS, 16 B per lane. LDS dest is wave-uniform base + lane*16.
static __device__ __forceinline__ void gll16(const unsigned short* g, unsigned short* l) {
    __builtin_amdgcn_global_load_lds(
        (const __attribute__((address_space(1))) unsigned int*)g,
        (__attribute__((address_space(3))) unsigned int*)l, 16, 0, 0);
}

// ---------------------------------------------------------------------------
// SWIZZLES (baked into GLOBAL layouts; all readers adjust):
//  - q/k rows (128 shorts = 16 x 16B blocks): block j of row t at j^(t&15).
//  - vtt rows (32 shorts = 4 blocks): block j of row h at j^((h>>1)&3).
//  - xt/wtt rows (32 shorts = 4 blocks): block j of row r at j^(r&3).
//
// R9 chunked partials; R11 single-buffer staging (230.7); R12 proj swizzle
// (218.9); R13 XCD batch affinity (208.7); R14 8-wave REGRESSED (TLP is
// the latency hider); R15 direct-L2 REGRESSED (scattered loads serialize);
// R16 dbuf-in-attn REGRESSED (LDS x2 -> occupancy /2).
// R17: fp16 q/k storage -> single-pass fp16 QK^T in stats/out (197.9,
// absmax 0.047 -- error model validated).
// R18: propagate fp16 upstream. x and W stored fp16 -> proj is a SINGLE
// fp16 MFMA pass for all z (was 3-pass split-bf16 for q/k): 7 -> 3 unit
// GEMM passes, staging 24->12 KB/iter uniform, LDS 48->24 KB. Added att
// error ~0.026 abs, below R17's fp16-storage quantization. stats/out
// byte-identical to R17-verified. Workspace map unchanged.
// ---------------------------------------------------------------------------

// ---------------------------------------------------------------------------
// Kernel 0: W (E,H) fp32 -> K-tiled fp16 wtt[z][ks][128 h][32 k],
// 16B blocks swizzled j^(h&3).
// ---------------------------------------------------------------------------
__global__ __launch_bounds__(256) void wtrans_kernel(
    const float* __restrict__ Wq, const float* __restrict__ Wk, const float* __restrict__ Wv,
    unsigned short* __restrict__ wtt)
{
    int t = blockIdx.x * 256 + threadIdx.x;   // 0..49151
    int kc8 = t & 3;
    int hh = (t >> 2) & 127;
    int ks = (t >> 9) & 31;
    int z = t >> 14;
    const float* W = (z == 0) ? Wq : ((z == 1) ? Wk : Wv);
    short8 h8;
#pragma unroll
    for (int j = 0; j < 8; j++) {
        int e = ks * 32 + kc8 * 8 + j;
        h8[j] = (short)f2h(W[(size_t)e * Hn + hh]);
    }
    size_t d = (((size_t)z * 32 + ks) * 4096) + (size_t)hh * 32
             + (size_t)(kc8 ^ (hh & 3)) * 8;            // R12 swizzle
    *(short8*)(wtt + d) = h8;
}

// ---------------------------------------------------------------------------
// Kernel 0b: x fp32 -> K-tiled fp16 xt[mt][ks][64 r][32 k],
// 16B blocks swizzled j^(r&3).
// ---------------------------------------------------------------------------
__global__ __launch_bounds__(256) void xconv_kernel(
    const float* __restrict__ x, unsigned short* __restrict__ xt)
{
    int g = blockIdx.x * 256 + threadIdx.x;   // 0..2097151
    int kc8 = g & 3;
    int rr = (g >> 2) & 63;
    int ks = (g >> 8) & 31;
    int mt = g >> 13;
    size_t src = ((size_t)mt * 64 + rr) * En + ks * 32 + kc8 * 8;
    float4v f0 = *(const float4v*)(x + src);
    float4v f1 = *(const float4v*)(x + src + 4);
    short8 h;
#pragma unroll
    for (int j = 0; j < 4; j++) {
        h[j] = (short)f2h(f0[j]);
        h[j + 4] = (short)f2h(f1[j]);
    }
    size_t d = (size_t)(g >> 2) * 32 + (size_t)(kc8 ^ (rr & 3)) * 8;  // R12
    *(short8*)(xt + d) = h;
}

// ---------------------------------------------------------------------------
// Kernel 1: projections, single-pass fp16 LDS double-buffered GEMM (R18).
// Staging 12 chunks/iter uniform (A 4 + B 8), 3 per wave; LDS 24 KB.
// Swizzle-aware fragment reads (kg ^ (c15&3)). Epilogue: q/k fp16 with
// row swizzle; v bf16 s-chunk-tiled vtt (unchanged from R17).
// ---------------------------------------------------------------------------
__global__ __launch_bounds__(256) void proj_kernel(
    const unsigned short* __restrict__ xt, const unsigned short* __restrict__ wtt,
    unsigned short* __restrict__ qf, unsigned short* __restrict__ kf,
    unsigned short* __restrict__ vtt)
{
    __shared__ __align__(16) unsigned short lds[2][6144];  // 24 KB
    int z = blockIdx.y;
    int mt = blockIdx.x;                       // 0..255
    int tid = threadIdx.x;
    int wave = tid >> 6, lane = tid & 63;
    int c15 = lane & 15, kg = lane >> 4;
    int sb = c15 & 3;                          // read-swizzle selector
    int mrow = wave >> 1, ncol = wave & 1;     // 2x2 wave grid

    const unsigned short* A0 = xt + (size_t)mt * 32 * 2048;
    const unsigned short* B0 = wtt + (size_t)z * 32 * 4096;

    float4v acc[2][4];
#pragma unroll
    for (int i = 0; i < 2; i++)
#pragma unroll
        for (int j = 0; j < 4; j++) acc[i][j] = (float4v)0.0f;

    // hoisted staging cursors: 3 chunks/wave (12 total: A=4, B=8)
    const unsigned short* gcur[3];
    int lbo[3];
    int gstep[3];
#pragma unroll
    for (int i = 0; i < 3; i++) {
        int ch = wave * 3 + i;   // 0..11
        if (ch < 4) { gcur[i] = A0 + ch * 512;       lbo[i] = ch * 512;        gstep[i] = 2048; }
        else        { gcur[i] = B0 + (ch - 4) * 512; lbo[i] = 2048 + (ch - 4) * 512; gstep[i] = 4096; }
    }
    int lo8 = lane * 8;

    auto stage = [&](int buf) {
        unsigned short* Lb = lds[0] + buf * 6144;
#pragma unroll
        for (int i = 0; i < 3; i++) {
            gll16(gcur[i] + lo8, Lb + lbo[i] + lo8);
            gcur[i] += gstep[i];
        }
    };

    stage(0);

    for (int ks = 0; ks < 32; ks++) {
        __syncthreads();
        if (ks + 1 < 32) stage((ks + 1) & 1);
        const unsigned short* Lb = lds[ks & 1];

        half8 ah[2], bh[4];
#pragma unroll
        for (int mi = 0; mi < 2; mi++) {
            int row = mrow * 32 + mi * 16 + c15;
            ah[mi] = *(const half8*)(Lb + row * 32 + (kg ^ sb) * 8);
        }
#pragma unroll
        for (int ni = 0; ni < 4; ni++) {
            int row = ncol * 64 + ni * 16 + c15;
            bh[ni] = *(const half8*)(Lb + 2048 + row * 32 + (kg ^ sb) * 8);
        }
#pragma unroll
        for (int mi = 0; mi < 2; mi++)
#pragma unroll
            for (int ni = 0; ni < 4; ni++)
                acc[mi][ni] = MFMA16F(ah[mi], bh[ni], acc[mi][ni]);
    }

    if (z < 2) {
        unsigned short* oh = (z == 0) ? qf : kf;
#pragma unroll
        for (int mi = 0; mi < 2; mi++) {
#pragma unroll
            for (int ni = 0; ni < 4; ni++) {
                int h = ncol * 64 + ni * 16 + c15;
#pragma unroll
                for (int r = 0; r < 4; r++) {
                    int t = mt * 64 + mrow * 32 + mi * 16 + kg * 4 + r;
                    // swizzled: block (h>>3) of row t -> (h>>3) ^ (t&15)
                    size_t o = (size_t)t * Hn + (((h >> 3) ^ (t & 15)) << 3) + (h & 7);
                    oh[o] = f2h(acc[mi][ni][r]);        // fp16
                }
            }
        }
    } else {
        int b = mt >> 5;
#pragma unroll
        for (int mi = 0; mi < 2; mi++) {
            int t0 = (mt & 31) * 64 + mrow * 32 + mi * 16 + kg * 4;
            int sc = t0 >> 5, so = t0 & 31;
#pragma unroll
            for (int ni = 0; ni < 4; ni++) {
                int h = ncol * 64 + ni * 16 + c15;
                short4v pk;
#pragma unroll
                for (int r = 0; r < 4; r++) pk[r] = (short)f2bf(acc[mi][ni][r]);
                // swizzled: block (so>>3) of row h -> (so>>3) ^ ((h>>1)&3)
                int so2 = ((((so >> 3) ^ ((h >> 1) & 3))) << 3) | (so & 7);
                *(short4v*)(vtt + (((size_t)b * 64 + sc) * 128 + h) * 32 + so2) = pk;
            }
        }
    }
}

// ---------------------------------------------------------------------------
// Kernel 2: column softmax stats PARTIALS. t-loop of column tile sj split
// into nch = ((31-sj)>>2)+1 even chunks (<=8 iters). Single-buffer staging,
// fp16 single-pass QK. grid (B, 144): XCD affinity. (R17-verified.)
// ---------------------------------------------------------------------------
__global__ __launch_bounds__(256) void stats_part_kernel(
    const unsigned short* __restrict__ qf, const unsigned short* __restrict__ kf,
    float* __restrict__ m_part, float* __restrict__ l_part)
{
    __shared__ __align__(16) unsigned short lds[4096];  // 8 KB, single buffer
    int tid = threadIdx.x;
    int wave = tid >> 6, lane = tid & 63;
    int c15 = lane & 15, kg = lane >> 4;
    int b = blockIdx.x;                       // XCD = b

    // map blockIdx.y -> (sj, ci); sj ascending = heavy first
    int rem = (int)blockIdx.y, sj, nch = 1;
    for (sj = 0; sj < 32; sj++) {
        nch = ((31 - sj) >> 2) + 1;
        if (rem < nch) break;
        rem -= nch;
    }
    int ci = rem;
    int c0 = 2 * sj;
    int len = 64 - c0;
    int cbase = len / nch, ext = len % nch;
    int cs = c0 + ci * cbase + (ci < ext ? ci : ext);
    int ce = cs + cbase + (ci < ext ? 1 : 0);

    int s_base = sj * 64 + wave * 16;

    // A fragments: wave's 16 k-rows (fp16); s&15 == c15
    half8 a[4];
    {
        int s = s_base + c15;
        const unsigned short* kr = kf + ((size_t)(b * Tn + s)) * Hn;
#pragma unroll
        for (int st = 0; st < 4; st++) {
            int off = ((st * 4 + kg) ^ c15) * 8;
            a[st] = *(const half8*)(kr + off);
        }
    }
    float m[4], l[4];
#pragma unroll
    for (int r = 0; r < 4; r++) { m[r] = -3.0e38f; l[r] = 0.0f; }

    auto stage = [&](int c) {
        const unsigned short* Qf = qf + ((size_t)b * Tn + c * 32) * Hn;
        int lo8 = lane * 8;
#pragma unroll
        for (int i = 0; i < 2; i++) {
            int ch = wave * 2 + i;   // 0..7
            gll16(Qf + ch * 512 + lo8, lds + ch * 512 + lo8);
        }
    };

    for (int c = cs; c < ce; c++) {
        stage(c);
        __syncthreads();   // stage complete
#pragma unroll
        for (int half = 0; half < 2; half++) {
            int t16 = c * 32 + half * 16;
            int tl = half * 16 + c15;
            float4v a1 = (float4v)0.0f;
#pragma unroll
            for (int st = 0; st < 4; st++) {
                // swizzled block ((st*4+kg) ^ (t&15)); t&15 == c15
                int off = tl * 128 + ((st * 4 + kg) ^ c15) * 8;
                half8 bh = *(const half8*)(lds + off);
                a1 = MFMA16F(a[st], bh, a1);
            }
            int t = t16 + c15;
#pragma unroll
            for (int r = 0; r < 4; r++) {
                float attv = a1[r] * SQRTH;
                int s_row = s_base + kg * 4 + r;
                bool valid = (t >= s_row);
                float cand = valid ? attv : -3.0e38f;
                float mn = fmaxf(m[r], cand);
                l[r] = l[r] * __expf(m[r] - mn) + (valid ? __expf(attv - mn) : 0.0f);
                m[r] = mn;
            }
        }
        __syncthreads();   // all reads done before next stage overwrites
    }
    // merge t-subsets across the 16 lanes sharing kg
#pragma unroll
    for (int mask = 1; mask < 16; mask <<= 1) {
#pragma unroll
        for (int r = 0; r < 4; r++) {
            float mo = __shfl_xor(m[r], mask);
            float lo2 = __shfl_xor(l[r], mask);
            float mn = fmaxf(m[r], mo);
            l[r] = l[r] * __expf(m[r] - mn) + lo2 * __expf(mo - mn);
            m[r] = mn;
        }
    }
    if (c15 == 0) {
#pragma unroll
        for (int r = 0; r < 4; r++) {
            int sl = wave * 16 + kg * 4 + r;           // 0..63 within tile
            size_t d = ((((size_t)b * 32 + sj) * 8 + ci) * 64) + sl;
            m_part[d] = m[r];
            l_part[d] = l[r];
        }
    }
}

// ---------------------------------------------------------------------------
// Kernel 2b: merge stats partials -> (m_st, il_st). 16384 columns.
// ---------------------------------------------------------------------------
__global__ __launch_bounds__(256) void stats_combine_kernel(
    const float* __restrict__ m_part, const float* __restrict__ l_part,
    float* __restrict__ m_st, float* __restrict__ il_st)
{
    int g = blockIdx.x * 256 + threadIdx.x;   // 0..16383
    int s = g & 2047, b = g >> 11;
    int sj = s >> 6, sl = s & 63;
    int nch = ((31 - sj) >> 2) + 1;
    size_t base = (((size_t)b * 32 + sj) * 8) * 64 + sl;
    float M = m_part[base];
    float L = l_part[base];
    for (int ci = 1; ci < nch; ci++) {
        float mi = m_part[base + (size_t)ci * 64];
        float li = l_part[base + (size_t)ci * 64];
        float mn = fmaxf(M, mi);
        L = L * __expf(M - mn) + li * __expf(mi - mn);
        M = mn;
    }
    m_st[(size_t)b * Tn + s] = M;
    il_st[(size_t)b * Tn + s] = 1.0f / L;
}

// ---------------------------------------------------------------------------
// Kernel 3: output PARTIALS. s-loop of row tile tj split into nch =
// (tj>>2)+1 even chunks (<=8 iters). Single-buffer staging, fp16 QK +
// bf16 PV. grid (B, 144): XCD affinity. (R17-verified.)
// ---------------------------------------------------------------------------
__global__ __launch_bounds__(256) void out_part_kernel(
    const unsigned short* __restrict__ qf, const unsigned short* __restrict__ kf,
    const unsigned short* __restrict__ vtt,
    const float* __restrict__ m_st, const float* __restrict__ il_st,
    float* __restrict__ part_out)
{
    __shared__ __align__(16) unsigned short lds[8192];       // 16 KB, single
    __shared__ __align__(16) unsigned short pbuf[4][16][40]; // 5 KB
    int tid = threadIdx.x;
    int wave = tid >> 6, lane = tid & 63;
    int c15 = lane & 15, kg = lane >> 4;
    int b = blockIdx.x;                       // XCD = b

    // map blockIdx.y -> (tj, ci); tj descending = heavy first
    int rem = (int)blockIdx.y, tj, nch = 1;
    for (tj = 31; tj >= 0; tj--) {
        nch = (tj >> 2) + 1;
        if (rem < nch) break;
        rem -= nch;
    }
    int ci = rem;
    int len = 2 * tj + 2;
    int cbase = len / nch, ext = len % nch;
    int cs = ci * cbase + (ci < ext ? ci : ext);
    int ce = cs + cbase + (ci < ext ? 1 : 0);

    int t_base = tj * 64 + wave * 16;

    // A fragments: wave's 16 q-rows (fp16); t&15 == c15
    half8 qa[4];
    {
        int t = t_base + c15;
        const unsigned short* qr = qf + ((size_t)(b * Tn + t)) * Hn;
#pragma unroll
        for (int st = 0; st < 4; st++) {
            int off = ((st * 4 + kg) ^ c15) * 8;
            qa[st] = *(const half8*)(qr + off);
        }
    }
    float4v oacc[8];
#pragma unroll
    for (int i = 0; i < 8; i++) oacc[i] = (float4v)0.0f;

    auto stage = [&](int c) {
        const unsigned short* Kf = kf + ((size_t)b * Tn + c * 32) * Hn;
        const unsigned short* Vv = vtt + ((size_t)b * 64 + c) * (128 * 32);
        int lo8 = lane * 8;
#pragma unroll
        for (int i = 0; i < 4; i++) {
            int ch = wave * 4 + i;   // 0..15
            const unsigned short* g;
            unsigned short* ld;
            if (ch < 8) { g = Kf + ch * 512;       ld = lds + ch * 512; }
            else        { g = Vv + (ch - 8) * 512; ld = lds + 4096 + (ch - 8) * 512; }
            gll16(g + lo8, ld + lo8);
        }
    };

    for (int c = cs; c < ce; c++) {
        stage(c);
        __syncthreads();   // stage complete
#pragma unroll
        for (int half = 0; half < 2; half++) {
            int s16 = c * 32 + half * 16;
            int sl = half * 16 + c15;
            float4v a1 = (float4v)0.0f;
#pragma unroll
            for (int st = 0; st < 4; st++) {
                // swizzled block ((st*4+kg) ^ (s&15)); s&15 == c15
                int off = sl * 128 + ((st * 4 + kg) ^ c15) * 8;
                half8 bh = *(const half8*)(lds + off);
                a1 = MFMA16F(qa[st], bh, a1);
            }
            float msv = m_st[b * Tn + s16 + c15];
            float ilv = il_st[b * Tn + s16 + c15];
#pragma unroll
            for (int r = 0; r < 4; r++) {
                int t = t_base + kg * 4 + r;
                float attv = a1[r] * SQRTH;
                // clamp: att <= column max for true data (ULP-exact safety)
                float earg = fminf(attv - msv, 0.0f);
                float p = (t >= s16 + c15) ? __expf(earg) * ilv : 0.0f;
                pbuf[wave][kg * 4 + r][c15 + half * 16] = f2bf(p);
            }
        }
        // C-layout -> A-layout via LDS (wave-internal, DS pipe in-order)
        short8 pa = *(const short8*)&pbuf[wave][c15][kg * 8];
#pragma unroll
        for (int nt = 0; nt < 8; nt++) {
            // vtt row h = nt*16+c15; swizzled block kg ^ ((h>>1)&3),
            // (h>>1)&3 == (c15>>1)&3 since nt*16 is a multiple of 8 in h>>1
            int voff = (nt * 16 + c15) * 32 + ((kg ^ ((c15 >> 1) & 3)) * 8);
            short8 vb = *(const short8*)(lds + 4096 + voff);
            oacc[nt] = MFMA16(pa, vb, oacc[nt]);
        }
        __syncthreads();   // all reads done before next stage overwrites
    }
    // partial tile store: part[b][tj][ci][t_local 64][h 128]
    float* po = part_out + ((((size_t)b * 32 + tj) * 8 + ci) * 64) * 128;
#pragma unroll
    for (int nt = 0; nt < 8; nt++) {
        int h = nt * 16 + c15;
#pragma unroll
        for (int r = 0; r < 4; r++) {
            int tl = wave * 16 + kg * 4 + r;
            po[(size_t)tl * 128 + h] = oacc[nt][r];
        }
    }
}

// ---------------------------------------------------------------------------
// Kernel 3b: sum output partials -> out. 2M floats, float4 loads/stores.
// ---------------------------------------------------------------------------
__global__ __launch_bounds__(256) void out_combine_kernel(
    const float* __restrict__ part_out, float* __restrict__ out)
{
    int g = blockIdx.x * 256 + threadIdx.x;   // 0..524287 (float4 units)
    int h4 = g & 31;
    int t = (g >> 5) & 2047;
    int b = g >> 16;
    int tj = t >> 6, tl = t & 63;
    int nch = (tj >> 2) + 1;
    const float4v* p = (const float4v*)(part_out
        + ((((size_t)b * 32 + tj) * 8) * 64 + tl) * 128) + h4;
    float4v acc = p[0];
    for (int ci = 1; ci < nch; ci++) acc += p[(size_t)ci * 2048];  // slot = 8192 floats
    *((float4v*)(out + ((size_t)b * Tn + t) * Hn) + h4) = acc;
}

// ---------------------------------------------------------------------------
extern "C" void kernel_launch(void* const* d_in, const int* in_sizes, int n_in,
                              void* d_out, int out_size, void* d_ws, size_t ws_size,
                              hipStream_t stream)
{
    (void)in_sizes; (void)n_in; (void)out_size; (void)ws_size;
    const float* x  = (const float*)d_in[0];
    const float* Wk = (const float*)d_in[1];
    const float* Wq = (const float*)d_in[2];
    const float* Wv = (const float*)d_in[3];
    float* out = (float*)d_out;

    const size_t NQ = (size_t)Bn * Tn * Hn;        // 2,097,152
    const size_t NX = (size_t)Bn * Tn * En;        // 16,777,216
    unsigned short* qf  = (unsigned short*)d_ws;   // fp16 q
    unsigned short* qlo = qf + NQ;                 // unused (kept layout)
    unsigned short* kf  = qlo + NQ;                // fp16 k
    unsigned short* klo = kf + NQ;                 // unused (kept layout)
    unsigned short* vtt  = klo + NQ;
    unsigned short* xt   = vtt + NQ;               // fp16 xt (was xt_hi)
    unsigned short* xt_lo = xt + NX;               // unused (kept layout)
    unsigned short* wtt  = xt_lo + NX;             // fp16 wtt (was wtt_hi)
    unsigned short* wtt_lo = wtt + (size_t)3 * Hn * En;  // unused region
    float* m_st  = (float*)(wtt_lo + (size_t)3 * Hn * En);
    float* il_st = m_st + (size_t)Bn * Tn;
    // total ws use: ~89.4 MB — identical extent to the validated R7 layout

    // Dead-after-proj aliases:
    //  part_out = xt region: 8*32*8*64*128 fp32 = 67.1 MB == sizeof(xt+xt_lo)
    //  m_part/l_part = wtt regions: 8*32*8*64 fp32 = 512 KB each (<= 768 KB)
    float* part_out = (float*)xt;
    float* m_part   = (float*)wtt;
    float* l_part   = (float*)wtt_lo;

    wtrans_kernel<<<dim3(192), 256, 0, stream>>>(Wq, Wk, Wv, wtt);
    xconv_kernel<<<dim3(8192), 256, 0, stream>>>(x, xt);
    proj_kernel<<<dim3(256, 3), 256, 0, stream>>>(xt, wtt, qf, kf, vtt);
    stats_part_kernel<<<dim3(Bn, 144), 256, 0, stream>>>(qf, kf, m_part, l_part);
    stats_combine_kernel<<<dim3(64), 256, 0, stream>>>(m_part, l_part, m_st, il_st);
    out_part_kernel<<<dim3(Bn, 144), 256, 0, stream>>>(qf, kf, vtt,
                                                       m_st, il_st, part_out);
    out_combine_kernel<<<dim3(2048), 256, 0, stream>>>(part_out, out);
}